// Round 6
// baseline (11897.543 us; speedup 1.0000x reference)
//
#include <hip/hip_runtime.h>
#include <math.h>

#define H    1024
#define H3   3072
#define DIN  512
#define VSZ  32000
#define SS   64
#define BB   128
#define TP   47
#define NROWS (TP*BB)      // 6016
#define VCHUNKS 250        // 32000 / 128
#define FMARGIN 0.1f
#define NBLK 256
#define HS   65536         // u32 per packed state step (128*1024/2)

typedef unsigned short u16;
typedef unsigned int u32;
typedef __bf16 bf16_t;
typedef bf16_t bf16x8 __attribute__((ext_vector_type(8)));
typedef float f32x4 __attribute__((ext_vector_type(4)));
typedef u16 u16x4 __attribute__((ext_vector_type(4)));
typedef u16 u16x8 __attribute__((ext_vector_type(8)));

#define MFMA __builtin_amdgcn_mfma_f32_16x16x32_bf16

__device__ inline u16 f2bf(float f){
    unsigned b = __float_as_uint(f);
    return (u16)((b + 0x7FFFu + ((b >> 16) & 1u)) >> 16);
}
__device__ inline float bf2f(u16 u){ return __uint_as_float(((unsigned)u) << 16); }
__device__ inline float sigm(float x){ return 1.f/(1.f + expf(-x)); }

__device__ inline void stoval(float* p, float v){ *p = v; }
__device__ inline void stoval(u16* p, float v){ *p = f2bf(v); }

// coherent (LLC) accessors — agent scope, relaxed
__device__ inline void cstore(u32* p, u32 v){ __hip_atomic_store(p, v, __ATOMIC_RELAXED, __HIP_MEMORY_SCOPE_AGENT); }
__device__ inline void cstoref(float* p, float v){ __hip_atomic_store(p, v, __ATOMIC_RELAXED, __HIP_MEMORY_SCOPE_AGENT); }
__device__ inline float cloadf(const float* p){ return __hip_atomic_load(p, __ATOMIC_RELAXED, __HIP_MEMORY_SCOPE_AGENT); }
__device__ inline u32 cloadu(const u32* p){ return __hip_atomic_load(p, __ATOMIC_RELAXED, __HIP_MEMORY_SCOPE_AGENT); }

// grid barrier: __syncthreads drains each wave's vmcnt (compiler emits s_waitcnt before
// s_barrier), all cross-phase data is LLC-coherent (write-through atomics), so the
// flag protocol needs only relaxed atomics — no L2 writeback/invalidate => weights stay hot.
__device__ inline void gbar(u32* bar, u32* mygen, int tid){
    __syncthreads();
    if (tid == 0){
        u32 tgt = ++(*mygen);
        __builtin_amdgcn_s_waitcnt(0);
        u32 old = __hip_atomic_fetch_add(&bar[0], 1u, __ATOMIC_RELAXED, __HIP_MEMORY_SCOPE_AGENT);
        if (old == NBLK - 1u){
            __hip_atomic_store(&bar[0], 0u, __ATOMIC_RELAXED, __HIP_MEMORY_SCOPE_AGENT);
            __hip_atomic_store(&bar[1], tgt, __ATOMIC_RELAXED, __HIP_MEMORY_SCOPE_AGENT);
        } else {
            while (__hip_atomic_load(&bar[1], __ATOMIC_RELAXED, __HIP_MEMORY_SCOPE_AGENT) < tgt)
                __builtin_amdgcn_s_sleep(2);
        }
    }
    __syncthreads();
    asm volatile("" ::: "memory");
}

// ---------- init helpers ----------

__global__ __launch_bounds__(128) void k_mask_sum(const float* __restrict__ mask, float* __restrict__ msum){
    int b = threadIdx.x;
    if (b < BB){ float s = 0.f; for (int i = 0; i < SS; i++) s += mask[i*BB + b]; msum[b] = s; }
}

__global__ __launch_bounds__(256) void k_mean_ctx(const float* __restrict__ ctx, const float* __restrict__ msum,
                                                  float* __restrict__ mean){
    int idx = blockIdx.x*256 + threadIdx.x;
    if (idx < BB*H){
        float s = 0.f;
        for (int i = 0; i < SS; i++) s += ctx[(size_t)i*BB*H + idx];
        mean[idx] = s / msum[idx / H];
    }
}

// f32 -> bf16 row-major
__global__ __launch_bounds__(256) void k_f32bf(const float* __restrict__ in, u16* __restrict__ out, int n4){
    int i = blockIdx.x*256 + threadIdx.x;
    if (i >= n4) return;
    float4 v = ((const float4*)in)[i];
    u16x4 o = { f2bf(v.x), f2bf(v.y), f2bf(v.z), f2bf(v.w) };
    ((u16x4*)out)[i] = o;
}

// pack h0 f32 -> hsHI[0] (u32 bf16-pairs) + hsF f32
__global__ __launch_bounds__(256) void k_pack_h0(const float* __restrict__ h0, u32* __restrict__ hsHI,
                                                 float* __restrict__ hsF){
    int i = blockIdx.x*256 + threadIdx.x;    // < 65536
    float v0 = h0[i*2], v1 = h0[i*2 + 1];
    hsHI[i] = (u32)f2bf(v0) | ((u32)f2bf(v1) << 16);
    hsF[i*2] = v0; hsF[i*2 + 1] = v1;
}

// row-major f32 (R x K) -> MFMA-fragment-ordered bf16
__global__ __launch_bounds__(256) void k_f2bf_frag(const float* __restrict__ in, u16* __restrict__ out,
                                                   int RK8, int K8){
    int t = blockIdx.x*256 + threadIdx.x;
    if (t >= RK8) return;
    int r = t / K8, k8 = t - r*K8;
    const float* p = in + (size_t)r*K8*8 + k8*8;
    float4 a = *(const float4*)p;
    float4 b = *(const float4*)(p + 4);
    size_t dst = ((size_t)(r >> 4)*(K8 >> 2) + (k8 >> 2))*512 + (size_t)((r & 15) + (k8 & 3)*16)*8;
    u16x8 o;
    o[0]=f2bf(a.x); o[1]=f2bf(a.y); o[2]=f2bf(a.z); o[3]=f2bf(a.w);
    o[4]=f2bf(b.x); o[5]=f2bf(b.y); o[6]=f2bf(b.z); o[7]=f2bf(b.w);
    *(u16x8*)(out + dst) = o;
}

// rows of 512 f32: L2-normalize -> frag-ordered bf16
__global__ __launch_bounds__(256) void k_rownorm_frag(const float* __restrict__ in, u16* __restrict__ out,
                                                      int nrows){
    int w = threadIdx.x >> 6, lane = threadIdx.x & 63;
    int row = blockIdx.x*4 + w;
    if (row >= nrows) return;
    const float* r = in + (size_t)row*512 + lane*8;
    float4 a = *(const float4*)r;
    float4 b = *(const float4*)(r + 4);
    float s = a.x*a.x + a.y*a.y + a.z*a.z + a.w*a.w
            + b.x*b.x + b.y*b.y + b.z*b.z + b.w*b.w;
    #pragma unroll
    for (int off = 32; off; off >>= 1) s += __shfl_xor(s, off);
    float inv = rsqrtf(s);
    size_t dst = ((size_t)(row >> 4)*16 + (lane >> 2))*512 + (size_t)((row & 15) + (lane & 3)*16)*8;
    u16x8 o;
    o[0]=f2bf(a.x*inv); o[1]=f2bf(a.y*inv); o[2]=f2bf(a.z*inv); o[3]=f2bf(a.w*inv);
    o[4]=f2bf(b.x*inv); o[5]=f2bf(b.y*inv); o[6]=f2bf(b.z*inv); o[7]=f2bf(b.w*inv);
    *(u16x8*)(out + dst) = o;
}

// gather emb_W[y[row]] -> frag-ordered bf16 (K=512)
__global__ __launch_bounds__(256) void k_emb_frag(const float* __restrict__ emb, const int* __restrict__ y,
                                                  u16* __restrict__ out){
    int w = threadIdx.x >> 6, lane = threadIdx.x & 63;
    int row = blockIdx.x*4 + w;            // < 6016
    int src = y[row];
    const float* r = emb + (size_t)src*512 + lane*8;
    float4 a = *(const float4*)r;
    float4 b = *(const float4*)(r + 4);
    size_t dst = ((size_t)(row >> 4)*16 + (lane >> 2))*512 + (size_t)((row & 15) + (lane & 3)*16)*8;
    u16x8 o;
    o[0]=f2bf(a.x); o[1]=f2bf(a.y); o[2]=f2bf(a.z); o[3]=f2bf(a.w);
    o[4]=f2bf(b.x); o[5]=f2bf(b.y); o[6]=f2bf(b.z); o[7]=f2bf(b.w);
    *(u16x8*)(out + dst) = o;
}

// ---------- fp32 GEMM (h0 init only) ----------
template<int ACT>
__global__ __launch_bounds__(256) void k_gemm_nt(const float* __restrict__ A, const float* __restrict__ W,
                                                 const float* __restrict__ bias, float* __restrict__ C,
                                                 int M, int N, int K){
    __shared__ float As[16][68];
    __shared__ float Ws[16][68];
    int tid = threadIdx.x;
    int bm = blockIdx.y*64, bn = blockIdx.x*64;
    int lr = tid >> 2;
    int lk = (tid & 3) * 4;
    int tr = (tid >> 4) * 4;
    int tc = (tid & 15) * 4;
    float acc[4][4] = {};
    const float* Abase = A + (size_t)(bm + lr)*K;
    const float* Wbase = W + (size_t)(bn + lr)*K;
    for (int k0 = 0; k0 < K; k0 += 16){
        float4 av = *(const float4*)(Abase + k0 + lk);
        float4 wv = *(const float4*)(Wbase + k0 + lk);
        __syncthreads();
        As[lk+0][lr]=av.x; As[lk+1][lr]=av.y; As[lk+2][lr]=av.z; As[lk+3][lr]=av.w;
        Ws[lk+0][lr]=wv.x; Ws[lk+1][lr]=wv.y; Ws[lk+2][lr]=wv.z; Ws[lk+3][lr]=wv.w;
        __syncthreads();
        #pragma unroll
        for (int kk = 0; kk < 16; kk++){
            float4 a = *(const float4*)&As[kk][tr];
            float4 w = *(const float4*)&Ws[kk][tc];
            acc[0][0] += a.x*w.x; acc[0][1] += a.x*w.y; acc[0][2] += a.x*w.z; acc[0][3] += a.x*w.w;
            acc[1][0] += a.y*w.x; acc[1][1] += a.y*w.y; acc[1][2] += a.y*w.z; acc[1][3] += a.y*w.w;
            acc[2][0] += a.z*w.x; acc[2][1] += a.z*w.y; acc[2][2] += a.z*w.z; acc[2][3] += a.z*w.w;
            acc[3][0] += a.w*w.x; acc[3][1] += a.w*w.y; acc[3][2] += a.w*w.z; acc[3][3] += a.w*w.w;
        }
    }
    #pragma unroll
    for (int i = 0; i < 4; i++){
        #pragma unroll
        for (int j = 0; j < 4; j++){
            float v = acc[i][j];
            if (bias) v += bias[bn + tc + j];
            if (ACT == 1) v = tanhf(v);
            C[(size_t)(bm + tr + i)*N + bn + tc + j] = v;
        }
    }
}

// ---------- batched bf16 MFMA GEMM (frag B; A frag or row-major bf16) ----------
template<int AFRAG, int ACT, typename OutT>
__global__ __launch_bounds__(256) void k_gemmf(const u16* __restrict__ A, const u16* __restrict__ B,
                                               const float* __restrict__ bias, OutT* __restrict__ C,
                                               int M, int N, int K){
    int tid = threadIdx.x, lane = tid & 63, w = tid >> 6;
    int wm = w >> 1, wn = w & 1;
    int row0 = blockIdx.y*128 + wm*64, col0 = blockIdx.x*128 + wn*64;
    int r16 = lane & 15, kg8 = (lane >> 4)*8, rg = (lane >> 4)*4;
    int K32 = K >> 5;
    f32x4 acc[4][4] = {};
    for (int k0 = 0; k0 < K32; k0++){
        bf16x8 af[4], bfv[4];
        #pragma unroll
        for (int i = 0; i < 4; i++){
            if (AFRAG) af[i] = *(const bf16x8*)(A + (((size_t)((row0 >> 4) + i)*K32 + k0) << 9) + lane*8);
            else       af[i] = *(const bf16x8*)(A + (size_t)(row0 + i*16 + r16)*K + k0*32 + kg8);
        }
        #pragma unroll
        for (int j = 0; j < 4; j++)
            bfv[j] = *(const bf16x8*)(B + (((size_t)((col0 >> 4) + j)*K32 + k0) << 9) + lane*8);
        #pragma unroll
        for (int i = 0; i < 4; i++)
            #pragma unroll
            for (int j = 0; j < 4; j++)
                acc[i][j] = MFMA(af[i], bfv[j], acc[i][j], 0, 0, 0);
    }
    #pragma unroll
    for (int i = 0; i < 4; i++){
        #pragma unroll
        for (int j = 0; j < 4; j++){
            #pragma unroll
            for (int r = 0; r < 4; r++){
                int row = row0 + i*16 + rg + r;
                int col = col0 + j*16 + r16;
                float v = acc[i][j][r];
                if (bias) v += bias[col];
                if (ACT) v = tanhf(v);
                stoval(C + (size_t)row*N + col, v);
            }
        }
    }
}

// ---------- persistent recurrence ----------
struct RB {
    const u16 *gi0, *Whh0, *Wh2c, *Wih1, *Whh1, *ctxp, *ctxb;
    const float *bhh0, *bih1, *bhh1, *vatt, *mask;
    u32 *hsHI, *h1HI, *ztHI;
    float *hsF, *h1F, *prF, *ghF;
    u16 *h2all;
    u32 *bar;
};

__global__ __launch_bounds__(256) void k_recur(RB a){
    const int tid = threadIdx.x, lane = tid & 63, wv = tid >> 6;
    const int role = wv & 1;
    const int aw = blockIdx.x*2 + (wv >> 1);       // 0..511
    const int rt = aw & 7, ct = aw >> 3;           // rt: row tile (16 b), ct: 0..63
    const int r16 = lane & 15, rg = (lane >> 4)*4;
    const int kq4 = (lane >> 4)*4;                 // u32 offset within k0-frag
    const int b3 = blockIdx.x >> 1, half = blockIdx.x & 1;
    u32 mygen = 0;
    __shared__ float ps[H];
    __shared__ float sal[SS];

    for (int t = 0; t < TP; t++){
        // ---- P1: h1 = GRU0(hs, gi0[t]) ---- (role 0 waves)
        if (role == 0){
            const u32* Ab = a.hsHI + (size_t)t*HS + (size_t)(rt*16 + r16)*512 + kq4;
            const u16* B0 = a.Whh0 + (size_t)(ct*32)*512 + lane*8;
            f32x4 ac0 = {}, ac1 = {}, ac2 = {};
            for (int k0 = 0; k0 < 32; k0++){
                bf16x8 av = *(const bf16x8*)(Ab + k0*16);
                bf16x8 b0 = *(const bf16x8*)(B0 + (size_t)k0*512);
                bf16x8 b1 = *(const bf16x8*)(B0 + (size_t)(64*32 + k0)*512);
                bf16x8 b2 = *(const bf16x8*)(B0 + (size_t)(128*32 + k0)*512);
                ac0 = MFMA(av, b0, ac0, 0, 0, 0);
                ac1 = MFMA(av, b1, ac1, 0, 0, 0);
                ac2 = MFMA(av, b2, ac2, 0, 0, 0);
            }
            const u16* gi = a.gi0 + (size_t)t*BB*H3;
            #pragma unroll
            for (int r = 0; r < 4; r++){
                int b = rt*16 + rg + r, j = ct*16 + r16;
                size_t gio = (size_t)b*H3 + j;
                float gr = bf2f(gi[gio]);
                float gz = bf2f(gi[gio + H]);
                float gn = bf2f(gi[gio + 2*H]);
                float hr = ac0[r] + a.bhh0[j];
                float hz = ac1[r] + a.bhh0[H + j];
                float hn = ac2[r] + a.bhh0[2*H + j];
                float hp = cloadf(a.hsF + (size_t)b*H + j);
                float rr = sigm(gr + hr), zz = sigm(gz + hz);
                float nn = tanhf(gn + rr*hn);
                float hv = (1.f - zz)*nn + zz*hp;
                cstoref(a.h1F + (size_t)b*H + j, hv);
                float pv = __shfl_xor(hv, 1);
                if (!(r16 & 1))
                    cstore(a.h1HI + (size_t)t*HS + (size_t)b*512 + (j >> 1),
                           (u32)f2bf(hv) | ((u32)f2bf(pv) << 16));
            }
        }
        gbar(a.bar, &mygen, tid);

        // ---- P2: proj = h1 @ Wh2c^T (role 0)  ||  gh1 = h1 @ Whh1^T (role 1) ----
        {
            const u32* Ab = a.h1HI + (size_t)t*HS + (size_t)(rt*16 + r16)*512 + kq4;
            if (role == 0){
                const u16* Bb = a.Wh2c + (size_t)ct*16384 + lane*8;
                f32x4 ac = {};
                for (int k0 = 0; k0 < 32; k0++){
                    bf16x8 av = *(const bf16x8*)(Ab + k0*16);
                    bf16x8 bv = *(const bf16x8*)(Bb + (size_t)k0*512);
                    ac = MFMA(av, bv, ac, 0, 0, 0);
                }
                #pragma unroll
                for (int r = 0; r < 4; r++){
                    int b = rt*16 + rg + r, j = ct*16 + r16;
                    cstoref(a.prF + (size_t)b*H + j, ac[r]);
                }
            } else {
                int cg = (aw >> 3)*3;
                #pragma unroll
                for (int q = 0; q < 3; q++){
                    int rtile = cg + q;             // 0..191
                    const u16* Bb = a.Whh1 + (size_t)rtile*16384 + lane*8;
                    f32x4 ac = {};
                    for (int k0 = 0; k0 < 32; k0++){
                        bf16x8 av = *(const bf16x8*)(Ab + k0*16);
                        bf16x8 bv = *(const bf16x8*)(Bb + (size_t)k0*512);
                        ac = MFMA(av, bv, ac, 0, 0, 0);
                    }
                    #pragma unroll
                    for (int r = 0; r < 4; r++){
                        int b = rt*16 + rg + r, jj = rtile*16 + r16;
                        cstoref(a.ghF + (size_t)b*H3 + jj, ac[r]);
                    }
                }
            }
        }
        gbar(a.bar, &mygen, tid);

        // ---- P3: attention for b = blockIdx>>1 (pair-duplicated scores, split z_t) ----
        {
            int b = b3;
            for (int i = tid; i < H; i += 256) ps[i] = cloadf(a.prF + (size_t)b*H + i);
            __syncthreads();
            for (int q = 0; q < 16; q++){
                int s = wv*16 + q;
                const u16* cp = a.ctxp + ((size_t)(s*BB + b))*H;
                float acc = 0.f;
                #pragma unroll
                for (int u = 0; u < 16; u++){
                    int hh = u*64 + lane;
                    acc += tanhf(bf2f(cp[hh]) + ps[hh]) * a.vatt[hh];
                }
                #pragma unroll
                for (int off = 32; off; off >>= 1) acc += __shfl_xor(acc, off);
                if (lane == 0) sal[s] = acc + ((a.mask[s*BB + b] > 0.f) ? 0.f : -1e9f);
            }
            __syncthreads();
            if (tid < 64){
                float v = sal[tid];
                float m = v;
                #pragma unroll
                for (int off = 32; off; off >>= 1) m = fmaxf(m, __shfl_xor(m, off));
                float e = expf(v - m);
                float su = e;
                #pragma unroll
                for (int off = 32; off; off >>= 1) su += __shfl_xor(su, off);
                sal[tid] = e / su;
            }
            __syncthreads();
            int j0 = half*512 + tid*2;
            float a0 = 0.f, a1 = 0.f;
            for (int s = 0; s < SS; s++){
                float al = sal[s];
                const u16* c = a.ctxb + ((size_t)(s*BB + b))*H + j0;
                a0 += al*bf2f(c[0]); a1 += al*bf2f(c[1]);
            }
            cstore(a.ztHI + (size_t)t*HS + (size_t)b*512 + (j0 >> 1),
                   (u32)f2bf(a0) | ((u32)f2bf(a1) << 16));
        }
        gbar(a.bar, &mygen, tid);

        // ---- P4: gi1 = zt @ Wih1^T; h2 = GRU1(gi1, gh1, h1) ---- (role 0)
        if (role == 0){
            const u32* Ab = a.ztHI + (size_t)t*HS + (size_t)(rt*16 + r16)*512 + kq4;
            const u16* Bi = a.Wih1 + (size_t)(ct*32)*512 + lane*8;
            f32x4 ai0 = {}, ai1 = {}, ai2 = {};
            for (int k0 = 0; k0 < 32; k0++){
                bf16x8 av = *(const bf16x8*)(Ab + k0*16);
                bf16x8 b0 = *(const bf16x8*)(Bi + (size_t)k0*512);
                bf16x8 b1 = *(const bf16x8*)(Bi + (size_t)(64*32 + k0)*512);
                bf16x8 b2 = *(const bf16x8*)(Bi + (size_t)(128*32 + k0)*512);
                ai0 = MFMA(av, b0, ai0, 0, 0, 0);
                ai1 = MFMA(av, b1, ai1, 0, 0, 0);
                ai2 = MFMA(av, b2, ai2, 0, 0, 0);
            }
            #pragma unroll
            for (int r = 0; r < 4; r++){
                int b = rt*16 + rg + r, j = ct*16 + r16;
                float gr = ai0[r] + a.bih1[j];
                float gz = ai1[r] + a.bih1[H + j];
                float gn = ai2[r] + a.bih1[2*H + j];
                float hr = cloadf(a.ghF + (size_t)b*H3 + j)       + a.bhh1[j];
                float hz = cloadf(a.ghF + (size_t)b*H3 + H + j)   + a.bhh1[H + j];
                float hn = cloadf(a.ghF + (size_t)b*H3 + 2*H + j) + a.bhh1[2*H + j];
                float h1v = cloadf(a.h1F + (size_t)b*H + j);
                float rr = sigm(gr + hr), zz = sigm(gz + hz);
                float nn = tanhf(gn + rr*hn);
                float hv = (1.f - zz)*nn + zz*h1v;
                cstoref(a.hsF + (size_t)b*H + j, hv);
                a.h2all[((size_t)t*BB + b)*H + j] = f2bf(hv);
                float pv = __shfl_xor(hv, 1);
                if (!(r16 & 1))
                    cstore(a.hsHI + (size_t)(t+1)*HS + (size_t)b*512 + (j >> 1),
                           (u32)f2bf(hv) | ((u32)f2bf(pv) << 16));
            }
        }
        gbar(a.bar, &mygen, tid);
    }
}

// ---------- fused final GEMM + row-max (excl tgt) + s_true ----------
__global__ __launch_bounds__(256) void k_final(const u16* __restrict__ logitf, const u16* __restrict__ Wf,
                                               const int* __restrict__ y, float* __restrict__ pmax,
                                               float* __restrict__ strue){
    __shared__ float red[128][2];
    int tid = threadIdx.x, w = tid >> 6, lane = tid & 63;
    int wm = w >> 1, wn = w & 1;
    int row0 = blockIdx.x*128 + wm*64;
    int col0 = blockIdx.y*128 + wn*64;
    int r16 = lane & 15, rg = (lane >> 4)*4;
    f32x4 acc[4][4] = {};
    for (int k0 = 0; k0 < 16; k0++){
        bf16x8 af[4], bfv[4];
        #pragma unroll
        for (int i = 0; i < 4; i++)
            af[i] = *(const bf16x8*)(logitf + (((size_t)((row0 >> 4) + i)*16 + k0) << 9) + lane*8);
        #pragma unroll
        for (int j = 0; j < 4; j++)
            bfv[j] = *(const bf16x8*)(Wf + (((size_t)((col0 >> 4) + j)*16 + k0) << 9) + lane*8);
        #pragma unroll
        for (int i = 0; i < 4; i++)
            #pragma unroll
            for (int j = 0; j < 4; j++)
                acc[i][j] = MFMA(af[i], bfv[j], acc[i][j], 0, 0, 0);
    }
    #pragma unroll
    for (int i = 0; i < 4; i++){
        #pragma unroll
        for (int r = 0; r < 4; r++){
            int row = row0 + i*16 + rg + r;
            int tgt = y[row + BB];
            float m = -1e30f;
            #pragma unroll
            for (int j = 0; j < 4; j++){
                float v = acc[i][j][r];
                int col = col0 + j*16 + r16;
                if (col == tgt){ strue[row] = v; v = -1e30f; }
                m = fmaxf(m, v);
            }
            m = fmaxf(m, __shfl_xor(m, 1));
            m = fmaxf(m, __shfl_xor(m, 2));
            m = fmaxf(m, __shfl_xor(m, 4));
            m = fmaxf(m, __shfl_xor(m, 8));
            if (r16 == 0) red[wm*64 + i*16 + rg + r][wn] = m;
        }
    }
    __syncthreads();
    if (tid < 128){
        float m = fmaxf(red[tid][0], red[tid][1]);
        pmax[(size_t)(blockIdx.x*128 + tid)*VCHUNKS + blockIdx.y] = m;
    }
}

__global__ __launch_bounds__(256) void k_loss(const float* __restrict__ pmax, const float* __restrict__ strue,
                                              const int* __restrict__ y, float* __restrict__ out){
    int R = blockIdx.x*256 + threadIdx.x;
    int lane = threadIdx.x & 63, wave = threadIdx.x >> 6;
    float l = 0.f;
    if (R < NROWS){
        int tgt = y[R + BB];
        if (tgt != 0){
            const float* pm = pmax + (size_t)R*VCHUNKS;
            float m = -1e30f;
            for (int i = 0; i < VCHUNKS; i++) m = fmaxf(m, pm[i]);
            l = fmaxf(FMARGIN - strue[R] + m, 0.f);
        }
    }
    #pragma unroll
    for (int off = 32; off; off >>= 1) l += __shfl_down(l, off);
    __shared__ float wsum[4];
    if (lane == 0) wsum[wave] = l;
    __syncthreads();
    if (threadIdx.x == 0) atomicAdd(out, wsum[0] + wsum[1] + wsum[2] + wsum[3]);
}

// ---------- launch ----------
extern "C" void kernel_launch(void* const* d_in, const int* in_sizes, int n_in,
                              void* d_out, int out_size, void* d_ws, size_t ws_size,
                              hipStream_t stream){
    const float* ctx    = (const float*)d_in[0];
    const float* mask   = (const float*)d_in[1];
    const int*   y      = (const int*)d_in[2];
    const float* emb_W  = (const float*)d_in[3];
    const float* W_init = (const float*)d_in[4];
    const float* b_init = (const float*)d_in[5];
    const float* W_ih0  = (const float*)d_in[6];
    const float* W_hh0  = (const float*)d_in[7];
    const float* b_ih0  = (const float*)d_in[8];
    const float* b_hh0  = (const float*)d_in[9];
    const float* W_c2c  = (const float*)d_in[10];
    const float* W_h2c  = (const float*)d_in[11];
    const float* v_att  = (const float*)d_in[12];
    const float* W_ih1  = (const float*)d_in[13];
    const float* W_hh1  = (const float*)d_in[14];
    const float* b_ih1  = (const float*)d_in[15];
    const float* b_hh1  = (const float*)d_in[16];
    const float* W_h2o  = (const float*)d_in[17];
    const float* b_h2o  = (const float*)d_in[18];
    const float* W_out  = (const float*)d_in[19];
    float* out = (float*)d_out;

    char* wsb = (char*)d_ws;
    size_t off = 0;
    auto alloc = [&](size_t bytes)->void*{
        void* p = (void*)(wsb + off);
        off = (off + bytes + 255) & ~(size_t)255;
        return p;
    };
    u16* Wih0f = (u16*)alloc((size_t)H3*DIN*2);
    u16* Whh0f = (u16*)alloc((size_t)H3*H*2);
    u16* Wih1f = (u16*)alloc((size_t)H3*H*2);
    u16* Whh1f = (u16*)alloc((size_t)H3*H*2);
    u16* Wh2cf = (u16*)alloc((size_t)H*H*2);
    u16* Wc2cf = (u16*)alloc((size_t)H*H*2);
    u16* Wh2of = (u16*)alloc((size_t)DIN*H*2);
    u16* Woutf = (u16*)alloc((size_t)VSZ*DIN*2);
    u16* ctxb  = (u16*)alloc((size_t)SS*BB*H*2);
    u16* ctxpb = (u16*)alloc((size_t)SS*BB*H*2);
    u16* embf  = (u16*)alloc((size_t)NROWS*DIN*2);
    u16* gi0b  = (u16*)alloc((size_t)NROWS*H3*2);   // reused after recurrence: logitf + logitfr + pmax
    u16* h2allb= (u16*)alloc((size_t)NROWS*H*2);
    u32* hsHI  = (u32*)alloc((size_t)(TP+1)*HS*4);
    u32* h1HI  = (u32*)alloc((size_t)TP*HS*4);
    u32* ztHI  = (u32*)alloc((size_t)TP*HS*4);
    float* hsF = (float*)alloc((size_t)BB*H*4);
    float* h1F = (float*)alloc((size_t)BB*H*4);
    float* prF = (float*)alloc((size_t)BB*H*4);
    float* ghF = (float*)alloc((size_t)BB*H3*4);
    u32* bar   = (u32*)alloc(256);
    float* strue  = (float*)alloc(NROWS*4);
    float* msum   = (float*)alloc(BB*4);
    float* meanc  = (float*)alloc((size_t)BB*H*4);
    float* h0f    = (float*)alloc((size_t)BB*H*4);

    // aliases inside gi0b (dead after recurrence): logitf f32 (12.3MB) + logitfr (6.2MB) + pmax (6.0MB)
    float* logitf  = (float*)gi0b;
    u16*   logitfr = (u16*)(gi0b + (size_t)NROWS*DIN*2);          // after 12.3MB of f32 (in u16 units: NROWS*DIN*2 u16s)
    float* pmax    = (float*)(gi0b + (size_t)NROWS*DIN*2 + (size_t)NROWS*DIN);

    hipMemsetAsync(d_out, 0, sizeof(float), stream);
    hipMemsetAsync(bar, 0, 256, stream);

    // ---- init ----
    hipLaunchKernelGGL(k_mask_sum, dim3(1), dim3(128), 0, stream, mask, msum);
    hipLaunchKernelGGL(k_mean_ctx, dim3(BB*H/256), dim3(256), 0, stream, ctx, msum, meanc);
    hipLaunchKernelGGL((k_gemm_nt<1>), dim3(H/64, BB/64), dim3(256), 0, stream,
                       meanc, W_init, b_init, h0f, BB, H, H);
    hipLaunchKernelGGL(k_pack_h0, dim3(HS/256), dim3(256), 0, stream, h0f, hsHI, hsF);

    hipLaunchKernelGGL(k_f2bf_frag, dim3(H3*DIN/8/256), dim3(256), 0, stream, W_ih0, Wih0f, H3*DIN/8, DIN/8);
    hipLaunchKernelGGL(k_f2bf_frag, dim3(H3*H/8/256), dim3(256), 0, stream, W_hh0, Whh0f, H3*H/8, H/8);
    hipLaunchKernelGGL(k_f2bf_frag, dim3(H3*H/8/256), dim3(256), 0, stream, W_ih1, Wih1f, H3*H/8, H/8);
    hipLaunchKernelGGL(k_f2bf_frag, dim3(H3*H/8/256), dim3(256), 0, stream, W_hh1, Whh1f, H3*H/8, H/8);
    hipLaunchKernelGGL(k_f2bf_frag, dim3(H*H/8/256), dim3(256), 0, stream, W_h2c, Wh2cf, H*H/8, H/8);
    hipLaunchKernelGGL(k_f2bf_frag, dim3(H*H/8/256), dim3(256), 0, stream, W_c2c, Wc2cf, H*H/8, H/8);
    hipLaunchKernelGGL(k_f2bf_frag, dim3(DIN*H/8/256), dim3(256), 0, stream, W_h2o, Wh2of, DIN*H/8, H/8);
    hipLaunchKernelGGL(k_rownorm_frag, dim3(VSZ/4), dim3(256), 0, stream, W_out, Woutf, VSZ);
    hipLaunchKernelGGL(k_f32bf, dim3(SS*BB*H/4/256), dim3(256), 0, stream, ctx, ctxb, SS*BB*H/4);
    hipLaunchKernelGGL(k_emb_frag, dim3(NROWS/4), dim3(256), 0, stream, emb_W, y, embf);

    // ---- batched GEMMs ----
    hipLaunchKernelGGL((k_gemmf<1,0,u16>), dim3(H3/128, NROWS/128), dim3(256), 0, stream,
                       embf, Wih0f, b_ih0, gi0b, NROWS, H3, DIN);
    hipLaunchKernelGGL((k_gemmf<0,0,u16>), dim3(H/128, SS*BB/128), dim3(256), 0, stream,
                       ctxb, Wc2cf, (const float*)nullptr, ctxpb, SS*BB, H, H);

    // ---- persistent cooperative recurrence ----
    RB rb;
    rb.gi0 = gi0b; rb.Whh0 = Whh0f; rb.Wh2c = Wh2cf; rb.Wih1 = Wih1f; rb.Whh1 = Whh1f;
    rb.ctxp = ctxpb; rb.ctxb = ctxb;
    rb.bhh0 = b_hh0; rb.bih1 = b_ih1; rb.bhh1 = b_hh1; rb.vatt = v_att; rb.mask = mask;
    rb.hsHI = hsHI; rb.h1HI = h1HI; rb.ztHI = ztHI;
    rb.hsF = hsF; rb.h1F = h1F; rb.prF = prF; rb.ghF = ghF;
    rb.h2all = h2allb; rb.bar = bar;
    void* kp[] = { (void*)&rb };
    hipLaunchCooperativeKernel((const void*)k_recur, dim3(NBLK), dim3(256), kp, 0, stream);

    // ---- output head ----
    hipLaunchKernelGGL((k_gemmf<0,1,float>), dim3(DIN/128, NROWS/128), dim3(256), 0, stream,
                       h2allb, Wh2of, b_h2o, logitf, NROWS, DIN, H);
    hipLaunchKernelGGL(k_rownorm_frag, dim3(NROWS/4), dim3(256), 0, stream, logitf, logitfr, NROWS);
    hipLaunchKernelGGL(k_final, dim3(NROWS/128, VSZ/128), dim3(256), 0, stream,
                       logitfr, Woutf, y, pmax, strue);
    hipLaunchKernelGGL(k_loss, dim3((NROWS + 255)/256), dim3(256), 0, stream, pmax, strue, y, out);
}

// Round 7
// 8065.502 us; speedup vs baseline: 1.4751x; 1.4751x over previous
//
#include <hip/hip_runtime.h>
#include <math.h>

#define H    1024
#define H3   3072
#define DIN  512
#define VSZ  32000
#define SS   64
#define BB   128
#define TP   47
#define NROWS (TP*BB)      // 6016
#define VCHUNKS 250        // 32000 / 128
#define FMARGIN 0.1f
#define NBLK 256
#define HS   65536         // u32 per packed state step (128*1024/2)

typedef unsigned short u16;
typedef unsigned int u32;
typedef __bf16 bf16_t;
typedef bf16_t bf16x8 __attribute__((ext_vector_type(8)));
typedef float f32x4 __attribute__((ext_vector_type(4)));
typedef u16 u16x4 __attribute__((ext_vector_type(4)));
typedef u16 u16x8 __attribute__((ext_vector_type(8)));

#define MFMA __builtin_amdgcn_mfma_f32_16x16x32_bf16

__device__ inline u16 f2bf(float f){
    unsigned b = __float_as_uint(f);
    return (u16)((b + 0x7FFFu + ((b >> 16) & 1u)) >> 16);
}
__device__ inline float bf2f(u16 u){ return __uint_as_float(((unsigned)u) << 16); }
__device__ inline float sigm(float x){ return 1.f/(1.f + expf(-x)); }

__device__ inline void stoval(float* p, float v){ *p = v; }
__device__ inline void stoval(u16* p, float v){ *p = f2bf(v); }

// coherent (LLC) accessors — agent scope, relaxed
__device__ inline void cstore(u32* p, u32 v){ __hip_atomic_store(p, v, __ATOMIC_RELAXED, __HIP_MEMORY_SCOPE_AGENT); }
__device__ inline void cstoref(float* p, float v){ __hip_atomic_store(p, v, __ATOMIC_RELAXED, __HIP_MEMORY_SCOPE_AGENT); }
__device__ inline float cloadf(const float* p){ return __hip_atomic_load(p, __ATOMIC_RELAXED, __HIP_MEMORY_SCOPE_AGENT); }

// grid barrier (proven in R6): __syncthreads drains per-wave counters; cross-phase
// data goes write-through to LLC via agent-scope atomics; flag protocol relaxed.
__device__ inline void gbar(u32* bar, u32* mygen, int tid){
    __syncthreads();
    if (tid == 0){
        u32 tgt = ++(*mygen);
        __builtin_amdgcn_s_waitcnt(0);
        u32 old = __hip_atomic_fetch_add(&bar[0], 1u, __ATOMIC_RELAXED, __HIP_MEMORY_SCOPE_AGENT);
        if (old == NBLK - 1u){
            __hip_atomic_store(&bar[0], 0u, __ATOMIC_RELAXED, __HIP_MEMORY_SCOPE_AGENT);
            __hip_atomic_store(&bar[1], tgt, __ATOMIC_RELAXED, __HIP_MEMORY_SCOPE_AGENT);
        } else {
            while (__hip_atomic_load(&bar[1], __ATOMIC_RELAXED, __HIP_MEMORY_SCOPE_AGENT) < tgt)
                __builtin_amdgcn_s_sleep(2);
        }
    }
    __syncthreads();
    asm volatile("" ::: "memory");
}

// ---------- init helpers ----------

__global__ __launch_bounds__(128) void k_mask_sum(const float* __restrict__ mask, float* __restrict__ msum){
    int b = threadIdx.x;
    if (b < BB){ float s = 0.f; for (int i = 0; i < SS; i++) s += mask[i*BB + b]; msum[b] = s; }
}

__global__ __launch_bounds__(256) void k_mean_ctx(const float* __restrict__ ctx, const float* __restrict__ msum,
                                                  float* __restrict__ mean){
    int idx = blockIdx.x*256 + threadIdx.x;
    if (idx < BB*H){
        float s = 0.f;
        for (int i = 0; i < SS; i++) s += ctx[(size_t)i*BB*H + idx];
        mean[idx] = s / msum[idx / H];
    }
}

__global__ __launch_bounds__(256) void k_f32bf(const float* __restrict__ in, u16* __restrict__ out, int n4){
    int i = blockIdx.x*256 + threadIdx.x;
    if (i >= n4) return;
    float4 v = ((const float4*)in)[i];
    u16x4 o = { f2bf(v.x), f2bf(v.y), f2bf(v.z), f2bf(v.w) };
    ((u16x4*)out)[i] = o;
}

// pack h0 f32 -> hsHI[0] (u32 bf16-pairs) + hsF f32
__global__ __launch_bounds__(256) void k_pack_h0(const float* __restrict__ h0, u32* __restrict__ hsHI,
                                                 float* __restrict__ hsF){
    int i = blockIdx.x*256 + threadIdx.x;    // < 65536
    float v0 = h0[i*2], v1 = h0[i*2 + 1];
    hsHI[i] = (u32)f2bf(v0) | ((u32)f2bf(v1) << 16);
    hsF[i*2] = v0; hsF[i*2 + 1] = v1;
}

// row-major f32 (R x K) -> MFMA-fragment-ordered bf16
__global__ __launch_bounds__(256) void k_f2bf_frag(const float* __restrict__ in, u16* __restrict__ out,
                                                   int RK8, int K8){
    int t = blockIdx.x*256 + threadIdx.x;
    if (t >= RK8) return;
    int r = t / K8, k8 = t - r*K8;
    const float* p = in + (size_t)r*K8*8 + k8*8;
    float4 a = *(const float4*)p;
    float4 b = *(const float4*)(p + 4);
    size_t dst = ((size_t)(r >> 4)*(K8 >> 2) + (k8 >> 2))*512 + (size_t)((r & 15) + (k8 & 3)*16)*8;
    u16x8 o;
    o[0]=f2bf(a.x); o[1]=f2bf(a.y); o[2]=f2bf(a.z); o[3]=f2bf(a.w);
    o[4]=f2bf(b.x); o[5]=f2bf(b.y); o[6]=f2bf(b.z); o[7]=f2bf(b.w);
    *(u16x8*)(out + dst) = o;
}

// rows of 512 f32: L2-normalize -> frag-ordered bf16
__global__ __launch_bounds__(256) void k_rownorm_frag(const float* __restrict__ in, u16* __restrict__ out,
                                                      int nrows){
    int w = threadIdx.x >> 6, lane = threadIdx.x & 63;
    int row = blockIdx.x*4 + w;
    if (row >= nrows) return;
    const float* r = in + (size_t)row*512 + lane*8;
    float4 a = *(const float4*)r;
    float4 b = *(const float4*)(r + 4);
    float s = a.x*a.x + a.y*a.y + a.z*a.z + a.w*a.w
            + b.x*b.x + b.y*b.y + b.z*b.z + b.w*b.w;
    #pragma unroll
    for (int off = 32; off; off >>= 1) s += __shfl_xor(s, off);
    float inv = rsqrtf(s);
    size_t dst = ((size_t)(row >> 4)*16 + (lane >> 2))*512 + (size_t)((row & 15) + (lane & 3)*16)*8;
    u16x8 o;
    o[0]=f2bf(a.x*inv); o[1]=f2bf(a.y*inv); o[2]=f2bf(a.z*inv); o[3]=f2bf(a.w*inv);
    o[4]=f2bf(b.x*inv); o[5]=f2bf(b.y*inv); o[6]=f2bf(b.z*inv); o[7]=f2bf(b.w*inv);
    *(u16x8*)(out + dst) = o;
}

// gather emb_W[y[row]] -> frag-ordered bf16 (K=512)
__global__ __launch_bounds__(256) void k_emb_frag(const float* __restrict__ emb, const int* __restrict__ y,
                                                  u16* __restrict__ out){
    int w = threadIdx.x >> 6, lane = threadIdx.x & 63;
    int row = blockIdx.x*4 + w;            // < 6016
    int src = y[row];
    const float* r = emb + (size_t)src*512 + lane*8;
    float4 a = *(const float4*)r;
    float4 b = *(const float4*)(r + 4);
    size_t dst = ((size_t)(row >> 4)*16 + (lane >> 2))*512 + (size_t)((row & 15) + (lane & 3)*16)*8;
    u16x8 o;
    o[0]=f2bf(a.x); o[1]=f2bf(a.y); o[2]=f2bf(a.z); o[3]=f2bf(a.w);
    o[4]=f2bf(b.x); o[5]=f2bf(b.y); o[6]=f2bf(b.z); o[7]=f2bf(b.w);
    *(u16x8*)(out + dst) = o;
}

// ---------- fp32 GEMM (h0 init only) ----------
template<int ACT>
__global__ __launch_bounds__(256) void k_gemm_nt(const float* __restrict__ A, const float* __restrict__ W,
                                                 const float* __restrict__ bias, float* __restrict__ C,
                                                 int M, int N, int K){
    __shared__ float As[16][68];
    __shared__ float Ws[16][68];
    int tid = threadIdx.x;
    int bm = blockIdx.y*64, bn = blockIdx.x*64;
    int lr = tid >> 2;
    int lk = (tid & 3) * 4;
    int tr = (tid >> 4) * 4;
    int tc = (tid & 15) * 4;
    float acc[4][4] = {};
    const float* Abase = A + (size_t)(bm + lr)*K;
    const float* Wbase = W + (size_t)(bn + lr)*K;
    for (int k0 = 0; k0 < K; k0 += 16){
        float4 av = *(const float4*)(Abase + k0 + lk);
        float4 wv = *(const float4*)(Wbase + k0 + lk);
        __syncthreads();
        As[lk+0][lr]=av.x; As[lk+1][lr]=av.y; As[lk+2][lr]=av.z; As[lk+3][lr]=av.w;
        Ws[lk+0][lr]=wv.x; Ws[lk+1][lr]=wv.y; Ws[lk+2][lr]=wv.z; Ws[lk+3][lr]=wv.w;
        __syncthreads();
        #pragma unroll
        for (int kk = 0; kk < 16; kk++){
            float4 a = *(const float4*)&As[kk][tr];
            float4 w = *(const float4*)&Ws[kk][tc];
            acc[0][0] += a.x*w.x; acc[0][1] += a.x*w.y; acc[0][2] += a.x*w.z; acc[0][3] += a.x*w.w;
            acc[1][0] += a.y*w.x; acc[1][1] += a.y*w.y; acc[1][2] += a.y*w.z; acc[1][3] += a.y*w.w;
            acc[2][0] += a.z*w.x; acc[2][1] += a.z*w.y; acc[2][2] += a.z*w.z; acc[2][3] += a.z*w.w;
            acc[3][0] += a.w*w.x; acc[3][1] += a.w*w.y; acc[3][2] += a.w*w.z; acc[3][3] += a.w*w.w;
        }
    }
    #pragma unroll
    for (int i = 0; i < 4; i++){
        #pragma unroll
        for (int j = 0; j < 4; j++){
            float v = acc[i][j];
            if (bias) v += bias[bn + tc + j];
            if (ACT == 1) v = tanhf(v);
            C[(size_t)(bm + tr + i)*N + bn + tc + j] = v;
        }
    }
}

// ---------- batched bf16 MFMA GEMM (frag B; A frag or row-major bf16) ----------
template<int AFRAG, int ACT, typename OutT>
__global__ __launch_bounds__(256) void k_gemmf(const u16* __restrict__ A, const u16* __restrict__ B,
                                               const float* __restrict__ bias, OutT* __restrict__ C,
                                               int M, int N, int K){
    int tid = threadIdx.x, lane = tid & 63, w = tid >> 6;
    int wm = w >> 1, wn = w & 1;
    int row0 = blockIdx.y*128 + wm*64, col0 = blockIdx.x*128 + wn*64;
    int r16 = lane & 15, kg8 = (lane >> 4)*8, rg = (lane >> 4)*4;
    int K32 = K >> 5;
    f32x4 acc[4][4] = {};
    for (int k0 = 0; k0 < K32; k0++){
        bf16x8 af[4], bfv[4];
        #pragma unroll
        for (int i = 0; i < 4; i++){
            if (AFRAG) af[i] = *(const bf16x8*)(A + (((size_t)((row0 >> 4) + i)*K32 + k0) << 9) + lane*8);
            else       af[i] = *(const bf16x8*)(A + (size_t)(row0 + i*16 + r16)*K + k0*32 + kg8);
        }
        #pragma unroll
        for (int j = 0; j < 4; j++)
            bfv[j] = *(const bf16x8*)(B + (((size_t)((col0 >> 4) + j)*K32 + k0) << 9) + lane*8);
        #pragma unroll
        for (int i = 0; i < 4; i++)
            #pragma unroll
            for (int j = 0; j < 4; j++)
                acc[i][j] = MFMA(af[i], bfv[j], acc[i][j], 0, 0, 0);
    }
    #pragma unroll
    for (int i = 0; i < 4; i++){
        #pragma unroll
        for (int j = 0; j < 4; j++){
            #pragma unroll
            for (int r = 0; r < 4; r++){
                int row = row0 + i*16 + rg + r;
                int col = col0 + j*16 + r16;
                float v = acc[i][j][r];
                if (bias) v += bias[col];
                if (ACT) v = tanhf(v);
                stoval(C + (size_t)row*N + col, v);
            }
        }
    }
}

// ---------- persistent recurrence with LDS-resident weights ----------
// Block weight map (frag-ordered 16-col tiles, 32KB each; K=1024):
//  b 0..63  : Whh0 gates {jt,64+jt,128+jt} @ 0/16384/32768, Whh1 tile b @ 49152
//  b 64..127: Wih1 gates {jt,...} @ 0/16384/32768, Whh1 tile b @ 49152
//  b128..191: Whh1 tile b @ 0
//  b192..255: Wh2c tile (b-192) @ 0
struct RC {
    const u16 *gi0, *Whh0, *Wh2c, *Wih1, *Whh1, *ctxp;
    const float *bhh0, *bih1, *bhh1, *vatt, *mask, *ctxf;
    u32 *hsHI, *h1HI, *ztHI;
    float *hsF, *h1F, *prF, *ghF;
    u16 *h2all;
    u32 *bar;
};

__global__ __launch_bounds__(256) void k_recur2(RC a){
    __shared__ u16 wlds[65536];      // 128 KB weight heap
    __shared__ float ps[H];
    __shared__ float sal[SS];
    const int tid = threadIdx.x, lane = tid & 63, wv = tid >> 6;
    const int bid = blockIdx.x;
    const int r16 = lane & 15, rg = (lane >> 4)*4, kq4 = (lane >> 4)*4;
    const int b3 = bid >> 1, half = bid & 1;
    u32 mygen = 0;

    {   // load weight slices into LDS (32KB per tile copy)
        auto cp32k = [&](const u16* gsrc, int tile, int base){
            const u32* s = (const u32*)(gsrc + (size_t)tile*16384);
            u32* d = (u32*)(wlds + base);
            #pragma unroll
            for (int i = 0; i < 32; i++) d[tid + i*256] = s[tid + i*256];
        };
        if (bid < 64){
            cp32k(a.Whh0, bid, 0); cp32k(a.Whh0, 64+bid, 16384); cp32k(a.Whh0, 128+bid, 32768);
            cp32k(a.Whh1, bid, 49152);
        } else if (bid < 128){
            int jt = bid - 64;
            cp32k(a.Wih1, jt, 0); cp32k(a.Wih1, 64+jt, 16384); cp32k(a.Wih1, 128+jt, 32768);
            cp32k(a.Whh1, bid, 49152);
        } else if (bid < 192){
            cp32k(a.Whh1, bid, 0);
        } else {
            cp32k(a.Wh2c, bid-192, 0);
        }
    }
    __syncthreads();
    const int whh1_base = (bid < 128) ? 49152 : 0;

    for (int t = 0; t < TP; t++){
        // ---- P1: GRU0 — blocks 0..63, jt=bid; wave wv = row-tile ----
        if (bid < 64){
            const u32* Ab = a.hsHI + (size_t)t*HS + (size_t)(wv*16 + r16)*512 + kq4;
            f32x4 ac0 = {}, ac1 = {}, ac2 = {};
            for (int k0 = 0; k0 < 32; k0++){
                bf16x8 av = *(const bf16x8*)(Ab + k0*16);
                bf16x8 b0 = *(const bf16x8*)(wlds + (k0*64 + lane)*8);
                bf16x8 b1 = *(const bf16x8*)(wlds + 16384 + (k0*64 + lane)*8);
                bf16x8 b2 = *(const bf16x8*)(wlds + 32768 + (k0*64 + lane)*8);
                ac0 = MFMA(av, b0, ac0, 0, 0, 0);
                ac1 = MFMA(av, b1, ac1, 0, 0, 0);
                ac2 = MFMA(av, b2, ac2, 0, 0, 0);
            }
            const u16* gi = a.gi0 + (size_t)t*BB*H3;
            #pragma unroll
            for (int r = 0; r < 4; r++){
                int b = wv*16 + rg + r, j = bid*16 + r16;
                float gr = bf2f(gi[(size_t)b*H3 + j]);
                float gz = bf2f(gi[(size_t)b*H3 + H + j]);
                float gn = bf2f(gi[(size_t)b*H3 + 2*H + j]);
                float hr = ac0[r] + a.bhh0[j];
                float hz = ac1[r] + a.bhh0[H + j];
                float hn = ac2[r] + a.bhh0[2*H + j];
                float hp = cloadf(a.hsF + (size_t)b*H + j);
                float rr = sigm(gr + hr), zz = sigm(gz + hz);
                float nn = tanhf(gn + rr*hn);
                float hv = (1.f - zz)*nn + zz*hp;
                cstoref(a.h1F + (size_t)b*H + j, hv);
                float pv = __shfl_xor(hv, 1);
                if (!(r16 & 1))
                    cstore(a.h1HI + (size_t)t*HS + (size_t)b*512 + (j >> 1),
                           (u32)f2bf(hv) | ((u32)f2bf(pv) << 16));
            }
        }
        gbar(a.bar, &mygen, tid);

        // ---- P2: gh1 (blocks 0..191) || proj (blocks 192..255) ----
        {
            const u32* Ab = a.h1HI + (size_t)t*HS + (size_t)(wv*16 + r16)*512 + kq4;
            if (bid < 192){
                const u16* Bb = wlds + whh1_base;
                f32x4 ac = {};
                for (int k0 = 0; k0 < 32; k0++){
                    bf16x8 av = *(const bf16x8*)(Ab + k0*16);
                    bf16x8 bv = *(const bf16x8*)(Bb + (k0*64 + lane)*8);
                    ac = MFMA(av, bv, ac, 0, 0, 0);
                }
                #pragma unroll
                for (int r = 0; r < 4; r++){
                    int b = wv*16 + rg + r, jj = bid*16 + r16;
                    cstoref(a.ghF + (size_t)b*H3 + jj, ac[r]);
                }
            } else {
                f32x4 ac = {};
                for (int k0 = 0; k0 < 32; k0++){
                    bf16x8 av = *(const bf16x8*)(Ab + k0*16);
                    bf16x8 bv = *(const bf16x8*)(wlds + (k0*64 + lane)*8);
                    ac = MFMA(av, bv, ac, 0, 0, 0);
                }
                #pragma unroll
                for (int r = 0; r < 4; r++){
                    int b = wv*16 + rg + r, j = (bid - 192)*16 + r16;
                    cstoref(a.prF + (size_t)b*H + j, ac[r]);
                }
            }
        }
        gbar(a.bar, &mygen, tid);

        // ---- P3: attention for b = bid>>1 (scores duplicated, z split by half) ----
        {
            int b = b3;
            for (int i = tid; i < H; i += 256) ps[i] = cloadf(a.prF + (size_t)b*H + i);
            __syncthreads();
            for (int q = 0; q < 16; q++){
                int s = wv*16 + q;
                const u16* cp = a.ctxp + ((size_t)(s*BB + b))*H;
                float acc = 0.f;
                #pragma unroll
                for (int u = 0; u < 16; u++){
                    int hh = u*64 + lane;
                    acc += tanhf(bf2f(cp[hh]) + ps[hh]) * a.vatt[hh];
                }
                #pragma unroll
                for (int off = 32; off; off >>= 1) acc += __shfl_xor(acc, off);
                if (lane == 0) sal[s] = acc + ((a.mask[s*BB + b] > 0.f) ? 0.f : -1e9f);
            }
            __syncthreads();
            if (tid < 64){
                float v = sal[tid];
                float m = v;
                #pragma unroll
                for (int off = 32; off; off >>= 1) m = fmaxf(m, __shfl_xor(m, off));
                float e = expf(v - m);
                float su = e;
                #pragma unroll
                for (int off = 32; off; off >>= 1) su += __shfl_xor(su, off);
                sal[tid] = e / su;
            }
            __syncthreads();
            int j0 = half*512 + tid*2;
            float a0 = 0.f, a1 = 0.f;
            for (int s = 0; s < SS; s++){
                float al = sal[s];
                float2 cv = *(const float2*)(a.ctxf + ((size_t)(s*BB + b))*H + j0);
                a0 += al*cv.x; a1 += al*cv.y;
            }
            cstore(a.ztHI + (size_t)t*HS + (size_t)b*512 + (j0 >> 1),
                   (u32)f2bf(a0) | ((u32)f2bf(a1) << 16));
        }
        gbar(a.bar, &mygen, tid);

        // ---- P4: GRU1 — blocks 64..127, jt=bid-64 ----
        if (bid >= 64 && bid < 128){
            int jt = bid - 64;
            const u32* Ab = a.ztHI + (size_t)t*HS + (size_t)(wv*16 + r16)*512 + kq4;
            f32x4 ac0 = {}, ac1 = {}, ac2 = {};
            for (int k0 = 0; k0 < 32; k0++){
                bf16x8 av = *(const bf16x8*)(Ab + k0*16);
                bf16x8 b0 = *(const bf16x8*)(wlds + (k0*64 + lane)*8);
                bf16x8 b1 = *(const bf16x8*)(wlds + 16384 + (k0*64 + lane)*8);
                bf16x8 b2 = *(const bf16x8*)(wlds + 32768 + (k0*64 + lane)*8);
                ac0 = MFMA(av, b0, ac0, 0, 0, 0);
                ac1 = MFMA(av, b1, ac1, 0, 0, 0);
                ac2 = MFMA(av, b2, ac2, 0, 0, 0);
            }
            #pragma unroll
            for (int r = 0; r < 4; r++){
                int b = wv*16 + rg + r, j = jt*16 + r16;
                float gr = ac0[r] + a.bih1[j];
                float gz = ac1[r] + a.bih1[H + j];
                float gn = ac2[r] + a.bih1[2*H + j];
                float hr = cloadf(a.ghF + (size_t)b*H3 + j)       + a.bhh1[j];
                float hz = cloadf(a.ghF + (size_t)b*H3 + H + j)   + a.bhh1[H + j];
                float hn = cloadf(a.ghF + (size_t)b*H3 + 2*H + j) + a.bhh1[2*H + j];
                float h1v = cloadf(a.h1F + (size_t)b*H + j);
                float rr = sigm(gr + hr), zz = sigm(gz + hz);
                float nn = tanhf(gn + rr*hn);
                float hv = (1.f - zz)*nn + zz*h1v;
                cstoref(a.hsF + (size_t)b*H + j, hv);
                a.h2all[((size_t)t*BB + b)*H + j] = f2bf(hv);
                float pv = __shfl_xor(hv, 1);
                if (!(r16 & 1))
                    cstore(a.hsHI + (size_t)(t+1)*HS + (size_t)b*512 + (j >> 1),
                           (u32)f2bf(hv) | ((u32)f2bf(pv) << 16));
            }
        }
        gbar(a.bar, &mygen, tid);
    }
}

// ---------- fused final GEMM + row-max (excl tgt) + s_true ----------
__global__ __launch_bounds__(256) void k_final(const u16* __restrict__ logitf, const u16* __restrict__ Wf,
                                               const int* __restrict__ y, float* __restrict__ pmax,
                                               float* __restrict__ strue){
    __shared__ float red[128][2];
    int tid = threadIdx.x, w = tid >> 6, lane = tid & 63;
    int wm = w >> 1, wn = w & 1;
    int row0 = blockIdx.x*128 + wm*64;
    int col0 = blockIdx.y*128 + wn*64;
    int r16 = lane & 15, rg = (lane >> 4)*4;
    f32x4 acc[4][4] = {};
    for (int k0 = 0; k0 < 16; k0++){
        bf16x8 af[4], bfv[4];
        #pragma unroll
        for (int i = 0; i < 4; i++)
            af[i] = *(const bf16x8*)(logitf + (((size_t)((row0 >> 4) + i)*16 + k0) << 9) + lane*8);
        #pragma unroll
        for (int j = 0; j < 4; j++)
            bfv[j] = *(const bf16x8*)(Wf + (((size_t)((col0 >> 4) + j)*16 + k0) << 9) + lane*8);
        #pragma unroll
        for (int i = 0; i < 4; i++)
            #pragma unroll
            for (int j = 0; j < 4; j++)
                acc[i][j] = MFMA(af[i], bfv[j], acc[i][j], 0, 0, 0);
    }
    #pragma unroll
    for (int i = 0; i < 4; i++){
        #pragma unroll
        for (int r = 0; r < 4; r++){
            int row = row0 + i*16 + rg + r;
            int tgt = y[row + BB];
            float m = -1e30f;
            #pragma unroll
            for (int j = 0; j < 4; j++){
                float v = acc[i][j][r];
                int col = col0 + j*16 + r16;
                if (col == tgt){ strue[row] = v; v = -1e30f; }
                m = fmaxf(m, v);
            }
            m = fmaxf(m, __shfl_xor(m, 1));
            m = fmaxf(m, __shfl_xor(m, 2));
            m = fmaxf(m, __shfl_xor(m, 4));
            m = fmaxf(m, __shfl_xor(m, 8));
            if (r16 == 0) red[wm*64 + i*16 + rg + r][wn] = m;
        }
    }
    __syncthreads();
    if (tid < 128){
        float m = fmaxf(red[tid][0], red[tid][1]);
        pmax[(size_t)(blockIdx.x*128 + tid)*VCHUNKS + blockIdx.y] = m;
    }
}

__global__ __launch_bounds__(256) void k_loss(const float* __restrict__ pmax, const float* __restrict__ strue,
                                              const int* __restrict__ y, float* __restrict__ out){
    int R = blockIdx.x*256 + threadIdx.x;
    int lane = threadIdx.x & 63, wave = threadIdx.x >> 6;
    float l = 0.f;
    if (R < NROWS){
        int tgt = y[R + BB];
        if (tgt != 0){
            const float* pm = pmax + (size_t)R*VCHUNKS;
            float m = -1e30f;
            for (int i = 0; i < VCHUNKS; i++) m = fmaxf(m, pm[i]);
            l = fmaxf(FMARGIN - strue[R] + m, 0.f);
        }
    }
    #pragma unroll
    for (int off = 32; off; off >>= 1) l += __shfl_down(l, off);
    __shared__ float wsum[4];
    if (lane == 0) wsum[wave] = l;
    __syncthreads();
    if (threadIdx.x == 0) atomicAdd(out, wsum[0] + wsum[1] + wsum[2] + wsum[3]);
}

// ---------- launch ----------
extern "C" void kernel_launch(void* const* d_in, const int* in_sizes, int n_in,
                              void* d_out, int out_size, void* d_ws, size_t ws_size,
                              hipStream_t stream){
    const float* ctx    = (const float*)d_in[0];
    const float* mask   = (const float*)d_in[1];
    const int*   y      = (const int*)d_in[2];
    const float* emb_W  = (const float*)d_in[3];
    const float* W_init = (const float*)d_in[4];
    const float* b_init = (const float*)d_in[5];
    const float* W_ih0  = (const float*)d_in[6];
    const float* W_hh0  = (const float*)d_in[7];
    const float* b_ih0  = (const float*)d_in[8];
    const float* b_hh0  = (const float*)d_in[9];
    const float* W_c2c  = (const float*)d_in[10];
    const float* W_h2c  = (const float*)d_in[11];
    const float* v_att  = (const float*)d_in[12];
    const float* W_ih1  = (const float*)d_in[13];
    const float* W_hh1  = (const float*)d_in[14];
    const float* b_ih1  = (const float*)d_in[15];
    const float* b_hh1  = (const float*)d_in[16];
    const float* W_h2o  = (const float*)d_in[17];
    const float* b_h2o  = (const float*)d_in[18];
    const float* W_out  = (const float*)d_in[19];
    float* out = (float*)d_out;

    char* wsb = (char*)d_ws;
    size_t off = 0;
    auto alloc = [&](size_t bytes)->void*{
        void* p = (void*)(wsb + off);
        off = (off + bytes + 255) & ~(size_t)255;
        return p;
    };
    u16* Wih0f = (u16*)alloc((size_t)H3*DIN*2);
    u16* Whh0f = (u16*)alloc((size_t)H3*H*2);
    u16* Wih1f = (u16*)alloc((size_t)H3*H*2);
    u16* Whh1f = (u16*)alloc((size_t)H3*H*2);
    u16* Wh2cf = (u16*)alloc((size_t)H*H*2);
    u16* Wc2cf = (u16*)alloc((size_t)H*H*2);
    u16* Wh2of = (u16*)alloc((size_t)DIN*H*2);
    u16* Woutf = (u16*)alloc((size_t)VSZ*DIN*2);
    u16* ctxb  = (u16*)alloc((size_t)SS*BB*H*2);
    u16* ctxpb = (u16*)alloc((size_t)SS*BB*H*2);
    u16* embf  = (u16*)alloc((size_t)NROWS*DIN*2);
    u16* gi0b  = (u16*)alloc((size_t)NROWS*H3*2);   // reused after recurrence
    u16* h2allb= (u16*)alloc((size_t)NROWS*H*2);
    u32* hsHI  = (u32*)alloc((size_t)(TP+1)*HS*4);
    u32* h1HI  = (u32*)alloc((size_t)TP*HS*4);
    u32* ztHI  = (u32*)alloc((size_t)TP*HS*4);
    float* hsF = (float*)alloc((size_t)BB*H*4);
    float* h1F = (float*)alloc((size_t)BB*H*4);
    float* prF = (float*)alloc((size_t)BB*H*4);
    float* ghF = (float*)alloc((size_t)BB*H3*4);
    u32* bar   = (u32*)alloc(256);
    float* strue  = (float*)alloc(NROWS*4);
    float* msum   = (float*)alloc(BB*4);
    float* meanc  = (float*)alloc((size_t)BB*H*4);
    float* h0f    = (float*)alloc((size_t)BB*H*4);

    // aliases inside gi0b (dead after recurrence)
    float* logitf  = (float*)gi0b;
    u16*   logitfr = (u16*)(gi0b + (size_t)NROWS*DIN*2);
    float* pmax    = (float*)(gi0b + (size_t)NROWS*DIN*2 + (size_t)NROWS*DIN);

    hipMemsetAsync(d_out, 0, sizeof(float), stream);
    hipMemsetAsync(bar, 0, 256, stream);

    // ---- init ----
    hipLaunchKernelGGL(k_mask_sum, dim3(1), dim3(128), 0, stream, mask, msum);
    hipLaunchKernelGGL(k_mean_ctx, dim3(BB*H/256), dim3(256), 0, stream, ctx, msum, meanc);
    hipLaunchKernelGGL((k_gemm_nt<1>), dim3(H/64, BB/64), dim3(256), 0, stream,
                       meanc, W_init, b_init, h0f, BB, H, H);
    hipLaunchKernelGGL(k_pack_h0, dim3(HS/256), dim3(256), 0, stream, h0f, hsHI, hsF);

    hipLaunchKernelGGL(k_f2bf_frag, dim3(H3*DIN/8/256), dim3(256), 0, stream, W_ih0, Wih0f, H3*DIN/8, DIN/8);
    hipLaunchKernelGGL(k_f2bf_frag, dim3(H3*H/8/256), dim3(256), 0, stream, W_hh0, Whh0f, H3*H/8, H/8);
    hipLaunchKernelGGL(k_f2bf_frag, dim3(H3*H/8/256), dim3(256), 0, stream, W_ih1, Wih1f, H3*H/8, H/8);
    hipLaunchKernelGGL(k_f2bf_frag, dim3(H3*H/8/256), dim3(256), 0, stream, W_hh1, Whh1f, H3*H/8, H/8);
    hipLaunchKernelGGL(k_f2bf_frag, dim3(H*H/8/256), dim3(256), 0, stream, W_h2c, Wh2cf, H*H/8, H/8);
    hipLaunchKernelGGL(k_f2bf_frag, dim3(H*H/8/256), dim3(256), 0, stream, W_c2c, Wc2cf, H*H/8, H/8);
    hipLaunchKernelGGL(k_f2bf_frag, dim3(DIN*H/8/256), dim3(256), 0, stream, W_h2o, Wh2of, DIN*H/8, H/8);
    hipLaunchKernelGGL(k_rownorm_frag, dim3(VSZ/4), dim3(256), 0, stream, W_out, Woutf, VSZ);
    hipLaunchKernelGGL(k_f32bf, dim3(SS*BB*H/4/256), dim3(256), 0, stream, ctx, ctxb, SS*BB*H/4);
    hipLaunchKernelGGL(k_emb_frag, dim3(NROWS/4), dim3(256), 0, stream, emb_W, y, embf);

    // ---- batched GEMMs ----
    hipLaunchKernelGGL((k_gemmf<1,0,u16>), dim3(H3/128, NROWS/128), dim3(256), 0, stream,
                       embf, Wih0f, b_ih0, gi0b, NROWS, H3, DIN);
    hipLaunchKernelGGL((k_gemmf<0,0,u16>), dim3(H/128, SS*BB/128), dim3(256), 0, stream,
                       ctxb, Wc2cf, (const float*)nullptr, ctxpb, SS*BB, H, H);

    // ---- persistent recurrence (LDS-resident weights) ----
    RC rc;
    rc.gi0 = gi0b; rc.Whh0 = Whh0f; rc.Wh2c = Wh2cf; rc.Wih1 = Wih1f; rc.Whh1 = Whh1f;
    rc.ctxp = ctxpb;
    rc.bhh0 = b_hh0; rc.bih1 = b_ih1; rc.bhh1 = b_hh1; rc.vatt = v_att; rc.mask = mask; rc.ctxf = ctx;
    rc.hsHI = hsHI; rc.h1HI = h1HI; rc.ztHI = ztHI;
    rc.hsF = hsF; rc.h1F = h1F; rc.prF = prF; rc.ghF = ghF;
    rc.h2all = h2allb; rc.bar = bar;
    void* kp[] = { (void*)&rc };
    hipLaunchCooperativeKernel((const void*)k_recur2, dim3(NBLK), dim3(256), kp, 0, stream);

    // ---- output head ----
    hipLaunchKernelGGL((k_gemmf<0,1,float>), dim3(DIN/128, NROWS/128), dim3(256), 0, stream,
                       h2allb, Wh2of, b_h2o, logitf, NROWS, DIN, H);
    hipLaunchKernelGGL(k_rownorm_frag, dim3(NROWS/4), dim3(256), 0, stream, logitf, logitfr, NROWS);
    hipLaunchKernelGGL(k_final, dim3(NROWS/128, VSZ/128), dim3(256), 0, stream,
                       logitfr, Woutf, y, pmax, strue);
    hipLaunchKernelGGL(k_loss, dim3((NROWS + 255)/256), dim3(256), 0, stream, pmax, strue, y, out);
}

// Round 8
// 5726.032 us; speedup vs baseline: 2.0778x; 1.4086x over previous
//
#include <hip/hip_runtime.h>
#include <math.h>

#define H    1024
#define H3   3072
#define DIN  512
#define VSZ  32000
#define SS   64
#define BB   128
#define TP   47
#define NROWS (TP*BB)      // 6016
#define VCHUNKS 250        // 32000 / 128
#define FMARGIN 0.1f
#define NBLK 256
#define HS   65536         // u32 per packed state step (128*1024/2)

typedef unsigned short u16;
typedef unsigned int u32;
typedef __bf16 bf16_t;
typedef bf16_t bf16x8 __attribute__((ext_vector_type(8)));
typedef float f32x4 __attribute__((ext_vector_type(4)));
typedef u16 u16x4 __attribute__((ext_vector_type(4)));
typedef u16 u16x8 __attribute__((ext_vector_type(8)));

#define MFMA __builtin_amdgcn_mfma_f32_16x16x32_bf16

__device__ inline u16 f2bf(float f){
    unsigned b = __float_as_uint(f);
    return (u16)((b + 0x7FFFu + ((b >> 16) & 1u)) >> 16);
}
__device__ inline float bf2f(u16 u){ return __uint_as_float(((unsigned)u) << 16); }
__device__ inline float sigm(float x){ return 1.f/(1.f + expf(-x)); }

__device__ inline void stoval(float* p, float v){ *p = v; }
__device__ inline void stoval(u16* p, float v){ *p = f2bf(v); }

// coherent (LLC) accessors — agent scope, relaxed
__device__ inline void cstore(u32* p, u32 v){ __hip_atomic_store(p, v, __ATOMIC_RELAXED, __HIP_MEMORY_SCOPE_AGENT); }
__device__ inline void cstoref(float* p, float v){ __hip_atomic_store(p, v, __ATOMIC_RELAXED, __HIP_MEMORY_SCOPE_AGENT); }
__device__ inline float cloadf(const float* p){ return __hip_atomic_load(p, __ATOMIC_RELAXED, __HIP_MEMORY_SCOPE_AGENT); }

// grid barrier (proven R6/R7): __syncthreads drains per-wave counters; cross-phase
// data goes write-through to LLC via agent-scope atomics (per-step-unique addresses
// for MFMA-consumed data -> plain loads are never stale).
__device__ inline void gbar(u32* bar, u32* mygen, int tid){
    __syncthreads();
    if (tid == 0){
        u32 tgt = ++(*mygen);
        __builtin_amdgcn_s_waitcnt(0);
        u32 old = __hip_atomic_fetch_add(&bar[0], 1u, __ATOMIC_RELAXED, __HIP_MEMORY_SCOPE_AGENT);
        if (old == NBLK - 1u){
            __hip_atomic_store(&bar[0], 0u, __ATOMIC_RELAXED, __HIP_MEMORY_SCOPE_AGENT);
            __hip_atomic_store(&bar[1], tgt, __ATOMIC_RELAXED, __HIP_MEMORY_SCOPE_AGENT);
        } else {
            while (__hip_atomic_load(&bar[1], __ATOMIC_RELAXED, __HIP_MEMORY_SCOPE_AGENT) < tgt)
                __builtin_amdgcn_s_sleep(2);
        }
    }
    __syncthreads();
    asm volatile("" ::: "memory");
}

// ---------- init helpers ----------

__global__ __launch_bounds__(128) void k_mask_sum(const float* __restrict__ mask, float* __restrict__ msum){
    int b = threadIdx.x;
    if (b < BB){ float s = 0.f; for (int i = 0; i < SS; i++) s += mask[i*BB + b]; msum[b] = s; }
}

__global__ __launch_bounds__(256) void k_mean_ctx(const float* __restrict__ ctx, const float* __restrict__ msum,
                                                  float* __restrict__ mean){
    int idx = blockIdx.x*256 + threadIdx.x;
    if (idx < BB*H){
        float s = 0.f;
        for (int i = 0; i < SS; i++) s += ctx[(size_t)i*BB*H + idx];
        mean[idx] = s / msum[idx / H];
    }
}

__global__ __launch_bounds__(256) void k_f32bf(const float* __restrict__ in, u16* __restrict__ out, int n4){
    int i = blockIdx.x*256 + threadIdx.x;
    if (i >= n4) return;
    float4 v = ((const float4*)in)[i];
    u16x4 o = { f2bf(v.x), f2bf(v.y), f2bf(v.z), f2bf(v.w) };
    ((u16x4*)out)[i] = o;
}

// pack h0 f32 -> hsHI/hsLO[0] (u32 bf16-pairs) + hsF f32
__global__ __launch_bounds__(256) void k_pack_h0(const float* __restrict__ h0, u32* __restrict__ hsHI,
                                                 u32* __restrict__ hsLO, float* __restrict__ hsF){
    int i = blockIdx.x*256 + threadIdx.x;    // < 65536
    float v0 = h0[i*2], v1 = h0[i*2 + 1];
    u16 a = f2bf(v0), b = f2bf(v1);
    hsHI[i] = (u32)a | ((u32)b << 16);
    hsLO[i] = (u32)f2bf(v0 - bf2f(a)) | ((u32)f2bf(v1 - bf2f(b)) << 16);
    hsF[i*2] = v0; hsF[i*2 + 1] = v1;
}

// row-major f32 (R x K) -> MFMA-fragment-ordered bf16
__global__ __launch_bounds__(256) void k_f2bf_frag(const float* __restrict__ in, u16* __restrict__ out,
                                                   int RK8, int K8){
    int t = blockIdx.x*256 + threadIdx.x;
    if (t >= RK8) return;
    int r = t / K8, k8 = t - r*K8;
    const float* p = in + (size_t)r*K8*8 + k8*8;
    float4 a = *(const float4*)p;
    float4 b = *(const float4*)(p + 4);
    size_t dst = ((size_t)(r >> 4)*(K8 >> 2) + (k8 >> 2))*512 + (size_t)((r & 15) + (k8 & 3)*16)*8;
    u16x8 o;
    o[0]=f2bf(a.x); o[1]=f2bf(a.y); o[2]=f2bf(a.z); o[3]=f2bf(a.w);
    o[4]=f2bf(b.x); o[5]=f2bf(b.y); o[6]=f2bf(b.z); o[7]=f2bf(b.w);
    *(u16x8*)(out + dst) = o;
}

// rows of 512 f32: L2-normalize -> frag-ordered bf16
__global__ __launch_bounds__(256) void k_rownorm_frag(const float* __restrict__ in, u16* __restrict__ out,
                                                      int nrows){
    int w = threadIdx.x >> 6, lane = threadIdx.x & 63;
    int row = blockIdx.x*4 + w;
    if (row >= nrows) return;
    const float* r = in + (size_t)row*512 + lane*8;
    float4 a = *(const float4*)r;
    float4 b = *(const float4*)(r + 4);
    float s = a.x*a.x + a.y*a.y + a.z*a.z + a.w*a.w
            + b.x*b.x + b.y*b.y + b.z*b.z + b.w*b.w;
    #pragma unroll
    for (int off = 32; off; off >>= 1) s += __shfl_xor(s, off);
    float inv = rsqrtf(s);
    size_t dst = ((size_t)(row >> 4)*16 + (lane >> 2))*512 + (size_t)((row & 15) + (lane & 3)*16)*8;
    u16x8 o;
    o[0]=f2bf(a.x*inv); o[1]=f2bf(a.y*inv); o[2]=f2bf(a.z*inv); o[3]=f2bf(a.w*inv);
    o[4]=f2bf(b.x*inv); o[5]=f2bf(b.y*inv); o[6]=f2bf(b.z*inv); o[7]=f2bf(b.w*inv);
    *(u16x8*)(out + dst) = o;
}

// gather emb_W[y[row]] -> frag-ordered bf16 (K=512)
__global__ __launch_bounds__(256) void k_emb_frag(const float* __restrict__ emb, const int* __restrict__ y,
                                                  u16* __restrict__ out){
    int w = threadIdx.x >> 6, lane = threadIdx.x & 63;
    int row = blockIdx.x*4 + w;            // < 6016
    int src = y[row];
    const float* r = emb + (size_t)src*512 + lane*8;
    float4 a = *(const float4*)r;
    float4 b = *(const float4*)(r + 4);
    size_t dst = ((size_t)(row >> 4)*16 + (lane >> 2))*512 + (size_t)((row & 15) + (lane & 3)*16)*8;
    u16x8 o;
    o[0]=f2bf(a.x); o[1]=f2bf(a.y); o[2]=f2bf(a.z); o[3]=f2bf(a.w);
    o[4]=f2bf(b.x); o[5]=f2bf(b.y); o[6]=f2bf(b.z); o[7]=f2bf(b.w);
    *(u16x8*)(out + dst) = o;
}

// ---------- fp32 GEMM (h0 init only) ----------
template<int ACT>
__global__ __launch_bounds__(256) void k_gemm_nt(const float* __restrict__ A, const float* __restrict__ W,
                                                 const float* __restrict__ bias, float* __restrict__ C,
                                                 int M, int N, int K){
    __shared__ float As[16][68];
    __shared__ float Ws[16][68];
    int tid = threadIdx.x;
    int bm = blockIdx.y*64, bn = blockIdx.x*64;
    int lr = tid >> 2;
    int lk = (tid & 3) * 4;
    int tr = (tid >> 4) * 4;
    int tc = (tid & 15) * 4;
    float acc[4][4] = {};
    const float* Abase = A + (size_t)(bm + lr)*K;
    const float* Wbase = W + (size_t)(bn + lr)*K;
    for (int k0 = 0; k0 < K; k0 += 16){
        float4 av = *(const float4*)(Abase + k0 + lk);
        float4 wv = *(const float4*)(Wbase + k0 + lk);
        __syncthreads();
        As[lk+0][lr]=av.x; As[lk+1][lr]=av.y; As[lk+2][lr]=av.z; As[lk+3][lr]=av.w;
        Ws[lk+0][lr]=wv.x; Ws[lk+1][lr]=wv.y; Ws[lk+2][lr]=wv.z; Ws[lk+3][lr]=wv.w;
        __syncthreads();
        #pragma unroll
        for (int kk = 0; kk < 16; kk++){
            float4 a = *(const float4*)&As[kk][tr];
            float4 w = *(const float4*)&Ws[kk][tc];
            acc[0][0] += a.x*w.x; acc[0][1] += a.x*w.y; acc[0][2] += a.x*w.z; acc[0][3] += a.x*w.w;
            acc[1][0] += a.y*w.x; acc[1][1] += a.y*w.y; acc[1][2] += a.y*w.z; acc[1][3] += a.y*w.w;
            acc[2][0] += a.z*w.x; acc[2][1] += a.z*w.y; acc[2][2] += a.z*w.z; acc[2][3] += a.z*w.w;
            acc[3][0] += a.w*w.x; acc[3][1] += a.w*w.y; acc[3][2] += a.w*w.z; acc[3][3] += a.w*w.w;
        }
    }
    #pragma unroll
    for (int i = 0; i < 4; i++){
        #pragma unroll
        for (int j = 0; j < 4; j++){
            float v = acc[i][j];
            if (bias) v += bias[bn + tc + j];
            if (ACT == 1) v = tanhf(v);
            C[(size_t)(bm + tr + i)*N + bn + tc + j] = v;
        }
    }
}

// ---------- batched bf16 MFMA GEMM (frag B; A frag or row-major bf16) ----------
template<int AFRAG, int ACT, typename OutT>
__global__ __launch_bounds__(256) void k_gemmf(const u16* __restrict__ A, const u16* __restrict__ B,
                                               const float* __restrict__ bias, OutT* __restrict__ C,
                                               int M, int N, int K){
    int tid = threadIdx.x, lane = tid & 63, w = tid >> 6;
    int wm = w >> 1, wn = w & 1;
    int row0 = blockIdx.y*128 + wm*64, col0 = blockIdx.x*128 + wn*64;
    int r16 = lane & 15, kg8 = (lane >> 4)*8, rg = (lane >> 4)*4;
    int K32 = K >> 5;
    f32x4 acc[4][4] = {};
    for (int k0 = 0; k0 < K32; k0++){
        bf16x8 af[4], bfv[4];
        #pragma unroll
        for (int i = 0; i < 4; i++){
            if (AFRAG) af[i] = *(const bf16x8*)(A + (((size_t)((row0 >> 4) + i)*K32 + k0) << 9) + lane*8);
            else       af[i] = *(const bf16x8*)(A + (size_t)(row0 + i*16 + r16)*K + k0*32 + kg8);
        }
        #pragma unroll
        for (int j = 0; j < 4; j++)
            bfv[j] = *(const bf16x8*)(B + (((size_t)((col0 >> 4) + j)*K32 + k0) << 9) + lane*8);
        #pragma unroll
        for (int i = 0; i < 4; i++)
            #pragma unroll
            for (int j = 0; j < 4; j++)
                acc[i][j] = MFMA(af[i], bfv[j], acc[i][j], 0, 0, 0);
    }
    #pragma unroll
    for (int i = 0; i < 4; i++){
        #pragma unroll
        for (int j = 0; j < 4; j++){
            #pragma unroll
            for (int r = 0; r < 4; r++){
                int row = row0 + i*16 + rg + r;
                int col = col0 + j*16 + r16;
                float v = acc[i][j][r];
                if (bias) v += bias[col];
                if (ACT) v = tanhf(v);
                stoval(C + (size_t)row*N + col, v);
            }
        }
    }
}

// ---------- persistent recurrence: LDS weights + XCD-local attention + hi/lo state ----------
// Block weight map (frag-ordered 16-col tiles, 32KB each; K=1024):
//  b 0..63  : Whh0 gates {bid,64+bid,128+bid} @ 0/16384/32768, Whh1 tile bid @ 49152
//  b 64..127: Wih1 gates @ 0/16384/32768, Whh1 tile bid @ 49152
//  b128..191: Whh1 tile bid @ 0
//  b192..255: Wh2c tile (bid-192) @ 0
// Attention: b = (bid&7)*16 + ((bid>>3)>>1), half = (bid>>3)&1  (XCD-local ctxp/ctx)
struct RD {
    const u16 *gi0, *Whh0, *Wh2c, *Wih1, *Whh1, *ctxp;
    const float *bhh0, *bih1, *bhh1, *vatt, *mask, *ctxf;
    u32 *hsHI, *hsLO, *h1HI, *h1LO, *ztHI, *ztLO;
    float *hsF, *h1F, *prF, *ghF;
    u16 *h2all;
    u32 *bar;
};

__global__ __launch_bounds__(512) void k_recur3(RD a){
    __shared__ u16 wlds[65536];      // 128 KB weight heap
    __shared__ float ps[H];
    __shared__ float vattL[H];
    __shared__ float sal[SS];
    __shared__ float zred[4][512];
    const int tid = threadIdx.x, lane = tid & 63, wv = tid >> 6;   // wv 0..7
    const int bid = blockIdx.x;
    const int r16 = lane & 15, rg = (lane >> 4)*4, kq4 = (lane >> 4)*4;
    const int ab = (bid & 7)*16 + ((bid >> 3) >> 1);   // attention batch
    const int ahalf = (bid >> 3) & 1;
    u32 mygen = 0;

    {   // load weight slices into LDS (32KB per tile copy, 512 threads)
        auto cp32k = [&](const u16* gsrc, int tile, int base){
            const u32* s = (const u32*)(gsrc + (size_t)tile*16384);
            u32* d = (u32*)(wlds + base);
            #pragma unroll
            for (int i = 0; i < 16; i++) d[tid + i*512] = s[tid + i*512];
        };
        if (bid < 64){
            cp32k(a.Whh0, bid, 0); cp32k(a.Whh0, 64+bid, 16384); cp32k(a.Whh0, 128+bid, 32768);
            cp32k(a.Whh1, bid, 49152);
        } else if (bid < 128){
            int jt = bid - 64;
            cp32k(a.Wih1, jt, 0); cp32k(a.Wih1, 64+jt, 16384); cp32k(a.Wih1, 128+jt, 32768);
            cp32k(a.Whh1, bid, 49152);
        } else if (bid < 192){
            cp32k(a.Whh1, bid, 0);
        } else {
            cp32k(a.Wh2c, bid-192, 0);
        }
        for (int i = tid; i < H; i += 512) vattL[i] = a.vatt[i];
    }
    __syncthreads();
    const int whh1_base = (bid < 128) ? 49152 : 0;

    for (int t = 0; t < TP; t++){
        // ---- P1: GRU0 — blocks 0..63 own col-tile bid; 8 waves = 8 row-tiles ----
        if (bid < 64){
            const u32* AbH = a.hsHI + (size_t)t*HS + (size_t)(wv*16 + r16)*512 + kq4;
            const u32* AbL = a.hsLO + (size_t)t*HS + (size_t)(wv*16 + r16)*512 + kq4;
            f32x4 ac0 = {}, ac1 = {}, ac2 = {};
            for (int k0 = 0; k0 < 32; k0++){
                bf16x8 ah = *(const bf16x8*)(AbH + k0*16);
                bf16x8 al = *(const bf16x8*)(AbL + k0*16);
                bf16x8 b0 = *(const bf16x8*)(wlds + (k0*64 + lane)*8);
                bf16x8 b1 = *(const bf16x8*)(wlds + 16384 + (k0*64 + lane)*8);
                bf16x8 b2 = *(const bf16x8*)(wlds + 32768 + (k0*64 + lane)*8);
                ac0 = MFMA(ah, b0, ac0, 0, 0, 0); ac0 = MFMA(al, b0, ac0, 0, 0, 0);
                ac1 = MFMA(ah, b1, ac1, 0, 0, 0); ac1 = MFMA(al, b1, ac1, 0, 0, 0);
                ac2 = MFMA(ah, b2, ac2, 0, 0, 0); ac2 = MFMA(al, b2, ac2, 0, 0, 0);
            }
            const u16* gi = a.gi0 + (size_t)t*BB*H3;
            #pragma unroll
            for (int r = 0; r < 4; r++){
                int b = wv*16 + rg + r, j = bid*16 + r16;
                float gr = bf2f(gi[(size_t)b*H3 + j]);           // b_ih0 pre-added
                float gz = bf2f(gi[(size_t)b*H3 + H + j]);
                float gn = bf2f(gi[(size_t)b*H3 + 2*H + j]);
                float hr = ac0[r] + a.bhh0[j];
                float hz = ac1[r] + a.bhh0[H + j];
                float hn = ac2[r] + a.bhh0[2*H + j];
                float hp = cloadf(a.hsF + (size_t)b*H + j);
                float rr = sigm(gr + hr), zz = sigm(gz + hz);
                float nn = tanhf(gn + rr*hn);
                float hv = (1.f - zz)*nn + zz*hp;
                cstoref(a.h1F + (size_t)b*H + j, hv);
                u16 hib = f2bf(hv);
                u16 lob = f2bf(hv - bf2f(hib));
                u32 hip = (u32)__shfl_xor((int)(u32)hib, 1);
                u32 lop = (u32)__shfl_xor((int)(u32)lob, 1);
                if (!(r16 & 1)){
                    cstore(a.h1HI + (size_t)t*HS + (size_t)b*512 + (j >> 1), (u32)hib | (hip << 16));
                    cstore(a.h1LO + (size_t)t*HS + (size_t)b*512 + (j >> 1), (u32)lob | (lop << 16));
                }
            }
        }
        gbar(a.bar, &mygen, tid);

        // ---- P2: gh1 (blocks 0..191) || proj (blocks 192..255); 8 waves = 8 row-tiles ----
        {
            const u32* AbH = a.h1HI + (size_t)t*HS + (size_t)(wv*16 + r16)*512 + kq4;
            const u32* AbL = a.h1LO + (size_t)t*HS + (size_t)(wv*16 + r16)*512 + kq4;
            const u16* Bb = wlds + (bid < 192 ? whh1_base : 0);
            f32x4 ac = {};
            for (int k0 = 0; k0 < 32; k0++){
                bf16x8 ah = *(const bf16x8*)(AbH + k0*16);
                bf16x8 al = *(const bf16x8*)(AbL + k0*16);
                bf16x8 bv = *(const bf16x8*)(Bb + (k0*64 + lane)*8);
                ac = MFMA(ah, bv, ac, 0, 0, 0); ac = MFMA(al, bv, ac, 0, 0, 0);
            }
            #pragma unroll
            for (int r = 0; r < 4; r++){
                int b = wv*16 + rg + r;
                if (bid < 192) cstoref(a.ghF + (size_t)b*H3 + bid*16 + r16, ac[r]);
                else           cstoref(a.prF + (size_t)b*H + (bid - 192)*16 + r16, ac[r]);
            }
        }
        gbar(a.bar, &mygen, tid);

        // ---- P3: attention for b=ab (XCD-local); scores duplicated, z_t split by half ----
        {
            int b = ab;
            for (int i = tid; i < H; i += 512) ps[i] = cloadf(a.prF + (size_t)b*H + i);
            __syncthreads();
            #pragma unroll
            for (int q = 0; q < 8; q++){
                int s = wv*8 + q;
                const u16* cp = a.ctxp + ((size_t)(s*BB + b))*H + lane*16;
                u16x8 c0 = *(const u16x8*)cp;
                u16x8 c1 = *(const u16x8*)(cp + 8);
                const float* pp = ps + lane*16;
                const float* vv = vattL + lane*16;
                float acc = 0.f;
                #pragma unroll
                for (int e = 0; e < 8; e++) acc += tanhf(bf2f(c0[e]) + pp[e]) * vv[e];
                #pragma unroll
                for (int e = 0; e < 8; e++) acc += tanhf(bf2f(c1[e]) + pp[8 + e]) * vv[8 + e];
                #pragma unroll
                for (int off = 32; off; off >>= 1) acc += __shfl_xor(acc, off);
                if (lane == 0) sal[s] = acc + ((a.mask[s*BB + b] > 0.f) ? 0.f : -1e9f);
            }
            __syncthreads();
            if (tid < 64){
                float v = sal[tid];
                float m = v;
                #pragma unroll
                for (int off = 32; off; off >>= 1) m = fmaxf(m, __shfl_xor(m, off));
                float e = expf(v - m);
                float su = e;
                #pragma unroll
                for (int off = 32; off; off >>= 1) su += __shfl_xor(su, off);
                sal[tid] = e / su;
            }
            __syncthreads();
            // z_t over f32 ctx: 4-way s-parallel, float4 per thread
            int cq = (tid & 127)*4, sg = tid >> 7;
            float4 z = {0.f, 0.f, 0.f, 0.f};
            for (int si = 0; si < 16; si++){
                int s = sg + si*4;
                float al = sal[s];
                float4 cv = *(const float4*)(a.ctxf + ((size_t)(s*BB + b))*H + ahalf*512 + cq);
                z.x += al*cv.x; z.y += al*cv.y; z.z += al*cv.z; z.w += al*cv.w;
            }
            *(float4*)&zred[sg][cq] = z;
            __syncthreads();
            if (tid < 256){
                int c2 = tid*2;
                float a0 = zred[0][c2]   + zred[1][c2]   + zred[2][c2]   + zred[3][c2];
                float a1 = zred[0][c2+1] + zred[1][c2+1] + zred[2][c2+1] + zred[3][c2+1];
                int j0 = ahalf*512 + c2;
                u16 h0b = f2bf(a0), h1b = f2bf(a1);
                cstore(a.ztHI + (size_t)t*HS + (size_t)b*512 + (j0 >> 1), (u32)h0b | ((u32)h1b << 16));
                cstore(a.ztLO + (size_t)t*HS + (size_t)b*512 + (j0 >> 1),
                       (u32)f2bf(a0 - bf2f(h0b)) | ((u32)f2bf(a1 - bf2f(h1b)) << 16));
            }
            __syncthreads();
        }
        gbar(a.bar, &mygen, tid);

        // ---- P4: GRU1 — blocks 64..127 own col-tile jt; 8 waves = 8 row-tiles ----
        if (bid >= 64 && bid < 128){
            int jt = bid - 64;
            const u32* AbH = a.ztHI + (size_t)t*HS + (size_t)(wv*16 + r16)*512 + kq4;
            const u32* AbL = a.ztLO + (size_t)t*HS + (size_t)(wv*16 + r16)*512 + kq4;
            f32x4 ac0 = {}, ac1 = {}, ac2 = {};
            for (int k0 = 0; k0 < 32; k0++){
                bf16x8 ah = *(const bf16x8*)(AbH + k0*16);
                bf16x8 al = *(const bf16x8*)(AbL + k0*16);
                bf16x8 b0 = *(const bf16x8*)(wlds + (k0*64 + lane)*8);
                bf16x8 b1 = *(const bf16x8*)(wlds + 16384 + (k0*64 + lane)*8);
                bf16x8 b2 = *(const bf16x8*)(wlds + 32768 + (k0*64 + lane)*8);
                ac0 = MFMA(ah, b0, ac0, 0, 0, 0); ac0 = MFMA(al, b0, ac0, 0, 0, 0);
                ac1 = MFMA(ah, b1, ac1, 0, 0, 0); ac1 = MFMA(al, b1, ac1, 0, 0, 0);
                ac2 = MFMA(ah, b2, ac2, 0, 0, 0); ac2 = MFMA(al, b2, ac2, 0, 0, 0);
            }
            #pragma unroll
            for (int r = 0; r < 4; r++){
                int b = wv*16 + rg + r, j = jt*16 + r16;
                float gr = ac0[r] + a.bih1[j];
                float gz = ac1[r] + a.bih1[H + j];
                float gn = ac2[r] + a.bih1[2*H + j];
                float hr = cloadf(a.ghF + (size_t)b*H3 + j)       + a.bhh1[j];
                float hz = cloadf(a.ghF + (size_t)b*H3 + H + j)   + a.bhh1[H + j];
                float hn = cloadf(a.ghF + (size_t)b*H3 + 2*H + j) + a.bhh1[2*H + j];
                float h1v = cloadf(a.h1F + (size_t)b*H + j);
                float rr = sigm(gr + hr), zz = sigm(gz + hz);
                float nn = tanhf(gn + rr*hn);
                float hv = (1.f - zz)*nn + zz*h1v;
                cstoref(a.hsF + (size_t)b*H + j, hv);
                a.h2all[((size_t)t*BB + b)*H + j] = f2bf(hv);
                u16 hib = f2bf(hv);
                u16 lob = f2bf(hv - bf2f(hib));
                u32 hip = (u32)__shfl_xor((int)(u32)hib, 1);
                u32 lop = (u32)__shfl_xor((int)(u32)lob, 1);
                if (!(r16 & 1)){
                    cstore(a.hsHI + (size_t)(t+1)*HS + (size_t)b*512 + (j >> 1), (u32)hib | (hip << 16));
                    cstore(a.hsLO + (size_t)(t+1)*HS + (size_t)b*512 + (j >> 1), (u32)lob | (lop << 16));
                }
            }
        }
        gbar(a.bar, &mygen, tid);
    }
}

// ---------- fused final GEMM + row-max (excl tgt) + s_true ----------
__global__ __launch_bounds__(256) void k_final(const u16* __restrict__ logitf, const u16* __restrict__ Wf,
                                               const int* __restrict__ y, float* __restrict__ pmax,
                                               float* __restrict__ strue){
    __shared__ float red[128][2];
    int tid = threadIdx.x, w = tid >> 6, lane = tid & 63;
    int wm = w >> 1, wn = w & 1;
    int row0 = blockIdx.x*128 + wm*64;
    int col0 = blockIdx.y*128 + wn*64;
    int r16 = lane & 15, rg = (lane >> 4)*4;
    f32x4 acc[4][4] = {};
    for (int k0 = 0; k0 < 16; k0++){
        bf16x8 af[4], bfv[4];
        #pragma unroll
        for (int i = 0; i < 4; i++)
            af[i] = *(const bf16x8*)(logitf + (((size_t)((row0 >> 4) + i)*16 + k0) << 9) + lane*8);
        #pragma unroll
        for (int j = 0; j < 4; j++)
            bfv[j] = *(const bf16x8*)(Wf + (((size_t)((col0 >> 4) + j)*16 + k0) << 9) + lane*8);
        #pragma unroll
        for (int i = 0; i < 4; i++)
            #pragma unroll
            for (int j = 0; j < 4; j++)
                acc[i][j] = MFMA(af[i], bfv[j], acc[i][j], 0, 0, 0);
    }
    #pragma unroll
    for (int i = 0; i < 4; i++){
        #pragma unroll
        for (int r = 0; r < 4; r++){
            int row = row0 + i*16 + rg + r;
            int tgt = y[row + BB];
            float m = -1e30f;
            #pragma unroll
            for (int j = 0; j < 4; j++){
                float v = acc[i][j][r];
                int col = col0 + j*16 + r16;
                if (col == tgt){ strue[row] = v; v = -1e30f; }
                m = fmaxf(m, v);
            }
            m = fmaxf(m, __shfl_xor(m, 1));
            m = fmaxf(m, __shfl_xor(m, 2));
            m = fmaxf(m, __shfl_xor(m, 4));
            m = fmaxf(m, __shfl_xor(m, 8));
            if (r16 == 0) red[wm*64 + i*16 + rg + r][wn] = m;
        }
    }
    __syncthreads();
    if (tid < 128){
        float m = fmaxf(red[tid][0], red[tid][1]);
        pmax[(size_t)(blockIdx.x*128 + tid)*VCHUNKS + blockIdx.y] = m;
    }
}

__global__ __launch_bounds__(256) void k_loss(const float* __restrict__ pmax, const float* __restrict__ strue,
                                              const int* __restrict__ y, float* __restrict__ out){
    int R = blockIdx.x*256 + threadIdx.x;
    int lane = threadIdx.x & 63, wave = threadIdx.x >> 6;
    float l = 0.f;
    if (R < NROWS){
        int tgt = y[R + BB];
        if (tgt != 0){
            const float* pm = pmax + (size_t)R*VCHUNKS;
            float m = -1e30f;
            for (int i = 0; i < VCHUNKS; i++) m = fmaxf(m, pm[i]);
            l = fmaxf(FMARGIN - strue[R] + m, 0.f);
        }
    }
    #pragma unroll
    for (int off = 32; off; off >>= 1) l += __shfl_down(l, off);
    __shared__ float wsum[4];
    if (lane == 0) wsum[wave] = l;
    __syncthreads();
    if (threadIdx.x == 0) atomicAdd(out, wsum[0] + wsum[1] + wsum[2] + wsum[3]);
}

// ---------- launch ----------
extern "C" void kernel_launch(void* const* d_in, const int* in_sizes, int n_in,
                              void* d_out, int out_size, void* d_ws, size_t ws_size,
                              hipStream_t stream){
    const float* ctx    = (const float*)d_in[0];
    const float* mask   = (const float*)d_in[1];
    const int*   y      = (const int*)d_in[2];
    const float* emb_W  = (const float*)d_in[3];
    const float* W_init = (const float*)d_in[4];
    const float* b_init = (const float*)d_in[5];
    const float* W_ih0  = (const float*)d_in[6];
    const float* W_hh0  = (const float*)d_in[7];
    const float* b_ih0  = (const float*)d_in[8];
    const float* b_hh0  = (const float*)d_in[9];
    const float* W_c2c  = (const float*)d_in[10];
    const float* W_h2c  = (const float*)d_in[11];
    const float* v_att  = (const float*)d_in[12];
    const float* W_ih1  = (const float*)d_in[13];
    const float* W_hh1  = (const float*)d_in[14];
    const float* b_ih1  = (const float*)d_in[15];
    const float* b_hh1  = (const float*)d_in[16];
    const float* W_h2o  = (const float*)d_in[17];
    const float* b_h2o  = (const float*)d_in[18];
    const float* W_out  = (const float*)d_in[19];
    float* out = (float*)d_out;

    char* wsb = (char*)d_ws;
    size_t off = 0;
    auto alloc = [&](size_t bytes)->void*{
        void* p = (void*)(wsb + off);
        off = (off + bytes + 255) & ~(size_t)255;
        return p;
    };
    u16* Wih0f = (u16*)alloc((size_t)H3*DIN*2);
    u16* Whh0f = (u16*)alloc((size_t)H3*H*2);
    u16* Wih1f = (u16*)alloc((size_t)H3*H*2);
    u16* Whh1f = (u16*)alloc((size_t)H3*H*2);
    u16* Wh2cf = (u16*)alloc((size_t)H*H*2);
    u16* Wc2cf = (u16*)alloc((size_t)H*H*2);
    u16* Wh2of = (u16*)alloc((size_t)DIN*H*2);
    u16* Woutf = (u16*)alloc((size_t)VSZ*DIN*2);
    u16* ctxb  = (u16*)alloc((size_t)SS*BB*H*2);
    u16* ctxpb = (u16*)alloc((size_t)SS*BB*H*2);
    u16* embf  = (u16*)alloc((size_t)NROWS*DIN*2);
    u16* gi0b  = (u16*)alloc((size_t)NROWS*H3*2);   // reused after recurrence
    u16* h2allb= (u16*)alloc((size_t)NROWS*H*2);
    u32* hsHI  = (u32*)alloc((size_t)(TP+1)*HS*4);
    u32* hsLO  = (u32*)alloc((size_t)(TP+1)*HS*4);
    u32* h1HI  = (u32*)alloc((size_t)TP*HS*4);
    u32* h1LO  = (u32*)alloc((size_t)TP*HS*4);
    u32* ztHI  = (u32*)alloc((size_t)TP*HS*4);
    u32* ztLO  = (u32*)alloc((size_t)TP*HS*4);
    float* hsF = (float*)alloc((size_t)BB*H*4);
    float* h1F = (float*)alloc((size_t)BB*H*4);
    float* prF = (float*)alloc((size_t)BB*H*4);
    float* ghF = (float*)alloc((size_t)BB*H3*4);
    u32* bar   = (u32*)alloc(256);
    float* strue  = (float*)alloc(NROWS*4);
    float* msum   = (float*)alloc(BB*4);
    float* meanc  = (float*)alloc((size_t)BB*H*4);
    float* h0f    = (float*)alloc((size_t)BB*H*4);

    // aliases inside gi0b (dead after recurrence)
    float* logitf  = (float*)gi0b;
    u16*   logitfr = (u16*)(gi0b + (size_t)NROWS*DIN*2);
    float* pmax    = (float*)(gi0b + (size_t)NROWS*DIN*2 + (size_t)NROWS*DIN);

    hipMemsetAsync(d_out, 0, sizeof(float), stream);
    hipMemsetAsync(bar, 0, 256, stream);

    // ---- init ----
    hipLaunchKernelGGL(k_mask_sum, dim3(1), dim3(128), 0, stream, mask, msum);
    hipLaunchKernelGGL(k_mean_ctx, dim3(BB*H/256), dim3(256), 0, stream, ctx, msum, meanc);
    hipLaunchKernelGGL((k_gemm_nt<1>), dim3(H/64, BB/64), dim3(256), 0, stream,
                       meanc, W_init, b_init, h0f, BB, H, H);
    hipLaunchKernelGGL(k_pack_h0, dim3(HS/256), dim3(256), 0, stream, h0f, hsHI, hsLO, hsF);

    hipLaunchKernelGGL(k_f2bf_frag, dim3(H3*DIN/8/256), dim3(256), 0, stream, W_ih0, Wih0f, H3*DIN/8, DIN/8);
    hipLaunchKernelGGL(k_f2bf_frag, dim3(H3*H/8/256), dim3(256), 0, stream, W_hh0, Whh0f, H3*H/8, H/8);
    hipLaunchKernelGGL(k_f2bf_frag, dim3(H3*H/8/256), dim3(256), 0, stream, W_ih1, Wih1f, H3*H/8, H/8);
    hipLaunchKernelGGL(k_f2bf_frag, dim3(H3*H/8/256), dim3(256), 0, stream, W_hh1, Whh1f, H3*H/8, H/8);
    hipLaunchKernelGGL(k_f2bf_frag, dim3(H*H/8/256), dim3(256), 0, stream, W_h2c, Wh2cf, H*H/8, H/8);
    hipLaunchKernelGGL(k_f2bf_frag, dim3(H*H/8/256), dim3(256), 0, stream, W_c2c, Wc2cf, H*H/8, H/8);
    hipLaunchKernelGGL(k_f2bf_frag, dim3(DIN*H/8/256), dim3(256), 0, stream, W_h2o, Wh2of, DIN*H/8, H/8);
    hipLaunchKernelGGL(k_rownorm_frag, dim3(VSZ/4), dim3(256), 0, stream, W_out, Woutf, VSZ);
    hipLaunchKernelGGL(k_f32bf, dim3(SS*BB*H/4/256), dim3(256), 0, stream, ctx, ctxb, SS*BB*H/4);
    hipLaunchKernelGGL(k_emb_frag, dim3(NROWS/4), dim3(256), 0, stream, emb_W, y, embf);

    // ---- batched GEMMs ----
    hipLaunchKernelGGL((k_gemmf<1,0,u16>), dim3(H3/128, NROWS/128), dim3(256), 0, stream,
                       embf, Wih0f, b_ih0, gi0b, NROWS, H3, DIN);
    hipLaunchKernelGGL((k_gemmf<0,0,u16>), dim3(H/128, SS*BB/128), dim3(256), 0, stream,
                       ctxb, Wc2cf, (const float*)nullptr, ctxpb, SS*BB, H, H);

    // ---- persistent recurrence ----
    RD rd;
    rd.gi0 = gi0b; rd.Whh0 = Whh0f; rd.Wh2c = Wh2cf; rd.Wih1 = Wih1f; rd.Whh1 = Whh1f;
    rd.ctxp = ctxpb;
    rd.bhh0 = b_hh0; rd.bih1 = b_ih1; rd.bhh1 = b_hh1; rd.vatt = v_att; rd.mask = mask; rd.ctxf = ctx;
    rd.hsHI = hsHI; rd.hsLO = hsLO; rd.h1HI = h1HI; rd.h1LO = h1LO; rd.ztHI = ztHI; rd.ztLO = ztLO;
    rd.hsF = hsF; rd.h1F = h1F; rd.prF = prF; rd.ghF = ghF;
    rd.h2all = h2allb; rd.bar = bar;
    void* kp[] = { (void*)&rd };
    hipLaunchCooperativeKernel((const void*)k_recur3, dim3(NBLK), dim3(512), kp, 0, stream);

    // ---- output head ----
    hipLaunchKernelGGL((k_gemmf<0,1,float>), dim3(DIN/128, NROWS/128), dim3(256), 0, stream,
                       h2allb, Wh2of, b_h2o, logitf, NROWS, DIN, H);
    hipLaunchKernelGGL(k_rownorm_frag, dim3(NROWS/4), dim3(256), 0, stream, logitf, logitfr, NROWS);
    hipLaunchKernelGGL(k_final, dim3(NROWS/128, VSZ/128), dim3(256), 0, stream,
                       logitfr, Woutf, y, pmax, strue);
    hipLaunchKernelGGL(k_loss, dim3((NROWS + 255)/256), dim3(256), 0, stream, pmax, strue, y, out);
}